// Round 1
// baseline (292.142 us; speedup 1.0000x reference)
//
#include <hip/hip_runtime.h>

// CVRP decoder v4, MI355X.
// Pipeline: convert -> gemm_kv -> gemm_q -> attn -> gemm_c -> s2_fused.
// v4: s2_fused latency restructure. The kernel is one resident round
// (1024 blocks = 4/CU), so block latency == kernel duration. Changes:
//   - __launch_bounds__(256,4): free 128-VGPR budget (grid-limited occupancy).
//   - Phase 1: B-fragments double-buffered at nt granularity (8 loads in
//     flight under the MFMA chain instead of ~1 at VGPR=52).
//   - Phase 2: cdist+ninf for all 4 rows prefetched before the barrier;
//     the 4 per-row exact binary searches run interleaved in lockstep
//     (fixed 30 iters) so the serial cmp->popc->select chains overlap.
// Selection / tie-break semantics identical to v3.

typedef unsigned short u16;
typedef unsigned int u32;
typedef unsigned long long u64;
typedef __attribute__((ext_vector_type(8))) short short8;
typedef __attribute__((ext_vector_type(4))) float f32x4;
typedef __attribute__((ext_vector_type(16))) float f32x16;
typedef __attribute__((ext_vector_type(4))) u32 u32x4;
typedef __attribute__((ext_vector_type(8))) u16 u16x8;

#define AS1U(p) ((const __attribute__((address_space(1))) u32*)(p))
#define AS3U(p) ((__attribute__((address_space(3))) u32*)(p))

#define QSCALE (0.25f * 1.44269504088896340736f)  // 1/sqrt(D) * log2(e)
#define LOG2E 1.44269504088896340736f
#define INV_SQRT2 0.70710678118654752440f

__device__ __forceinline__ u16 f2bf(float f) {
  u32 u = __builtin_bit_cast(u32, f);
  return (u16)((u + 0x7FFFu + ((u >> 16) & 1u)) >> 16);  // RNE
}

__device__ __forceinline__ u32 pack_bf(float a, float b) {
  u32 ua = __builtin_bit_cast(u32, a), ub = __builtin_bit_cast(u32, b);
  ua = ua + 0x7FFFu + ((ua >> 16) & 1u);
  ub = ub + 0x7FFFu + ((ub >> 16) & 1u);
  return __builtin_amdgcn_perm(ub, ua, 0x07060302u);
}

__device__ __forceinline__ u32 swz_off(u32 row, u32 k) {  // half-index
  u32 g = k >> 3;
  u32 pos = (g & ~7u) | ((g & 7u) ^ (row & 7u));
  return row * 256u + pos * 8u + (k & 7u);
}

__device__ __forceinline__ float fast_tanh(float x) {
  float e = __builtin_amdgcn_exp2f(x * (2.0f * LOG2E));
  return 1.0f - 2.0f * __builtin_amdgcn_rcpf(e + 1.0f);
}

// ---------------------------------------------------------------------------
// convert: fp32 -> bf16, one 8-element granule per thread, swizzled rows.
// ---------------------------------------------------------------------------
__global__ __launch_bounds__(256) void convert_kernel(
    const float* __restrict__ nodes, const float* __restrict__ last,
    const float* __restrict__ Wk, const float* __restrict__ Wv,
    const float* __restrict__ Wq, const float* __restrict__ Wc,
    u16* __restrict__ nodes_bf, u16* __restrict__ last_bf,
    u16* __restrict__ Wkv_bf, u16* __restrict__ Wq_bf,
    float* __restrict__ wq_last, u16* __restrict__ Wc_bf) {
  long i = (long)blockIdx.x * 256 + threadIdx.x;
  if (i < 524288) {  // nodes: 16384 rows x 32 granules
    u32 row = (u32)(i >> 5), g = (u32)(i & 31);
    const float4* s4 = (const float4*)nodes + i * 2;
    float4 v0 = s4[0], v1 = s4[1];
    u16x8 o = {f2bf(v0.x), f2bf(v0.y), f2bf(v0.z), f2bf(v0.w),
               f2bf(v1.x), f2bf(v1.y), f2bf(v1.z), f2bf(v1.w)};
    u32 pos = (g & ~7u) | ((g & 7u) ^ (row & 7u));
    *(u16x8*)(nodes_bf + row * 256 + pos * 8) = o;
  } else if (i < 1048576) {  // last
    long j = i - 524288;
    u32 row = (u32)(j >> 5), g = (u32)(j & 31);
    const float4* s4 = (const float4*)last + j * 2;
    float4 v0 = s4[0], v1 = s4[1];
    u16x8 o = {f2bf(v0.x), f2bf(v0.y), f2bf(v0.z), f2bf(v0.w),
               f2bf(v1.x), f2bf(v1.y), f2bf(v1.z), f2bf(v1.w)};
    u32 pos = (g & ~7u) | ((g & 7u) ^ (row & 7u));
    *(u16x8*)(last_bf + row * 256 + pos * 8) = o;
  } else if (i < 1064960) {  // Wkv: 512 rows (Wk | Wv)
    long j = i - 1048576;
    u32 row = (u32)(j >> 5), g = (u32)(j & 31);
    const float* src = (row < 256) ? (Wk + row * 256 + g * 8)
                                   : (Wv + (row - 256) * 256 + g * 8);
    u16x8 o;
    for (int q = 0; q < 8; q++) o[q] = f2bf(src[q]);
    u32 pos = (g & ~7u) | ((g & 7u) ^ (row & 7u));
    *(u16x8*)(Wkv_bf + row * 256 + pos * 8) = o;
  } else if (i < 1073152) {  // Wq main 256x256 (src stride 257)
    long j = i - 1064960;
    u32 row = (u32)(j >> 5), g = (u32)(j & 31);
    const float* src = Wq + row * 257 + g * 8;
    u16x8 o;
    for (int q = 0; q < 8; q++) o[q] = f2bf(src[q]);
    u32 pos = (g & ~7u) | ((g & 7u) ^ (row & 7u));
    *(u16x8*)(Wq_bf + row * 256 + pos * 8) = o;
  } else if (i < 1081344) {  // Wc 256x256
    long j = i - 1073152;
    u32 row = (u32)(j >> 5), g = (u32)(j & 31);
    const float* src = Wc + row * 256 + g * 8;
    u16x8 o;
    for (int q = 0; q < 8; q++) o[q] = f2bf(src[q]);
    u32 pos = (g & ~7u) | ((g & 7u) ^ (row & 7u));
    *(u16x8*)(Wc_bf + row * 256 + pos * 8) = o;
  } else if (i < 1081600) {  // Wq last column (fp32)
    long o = i - 1081344;
    wq_last[o] = Wq[o * 257 + 256];
  }
}

// ---------------------------------------------------------------------------
// proj core: block computes 128m x 64j, K=256. W j-tile (64x256, 32KB) staged
// once in LDS via DMA + single barrier; A-frags direct global->VGPR.
// Wave (2x2): 64m x 32j -> acc[4 msub][2 fj]. Zero in-loop barriers.
// ---------------------------------------------------------------------------
__device__ __forceinline__ void proj_core(
    const u16* __restrict__ Abase, const u16* __restrict__ Wbase,
    u16* Ws, f32x4 acc[4][2]) {
  const int t = threadIdx.x;
  const int lane = t & 63, w = t >> 6;
  const int wm = (w & 1) * 64, wj = (w >> 1) * 32;
  const int qq = lane >> 4, lr = lane & 15;
#pragma unroll
  for (int c = 0; c < 8; ++c)
    __builtin_amdgcn_global_load_lds(AS1U(Wbase + c * 2048 + t * 8),
                                     AS3U(Ws + c * 2048 + w * 512), 16, 0, 0);
#pragma unroll
  for (int ms = 0; ms < 4; ++ms)
    for (int fj = 0; fj < 2; ++fj) acc[ms][fj] = (f32x4){0.f, 0.f, 0.f, 0.f};
  __syncthreads();
#pragma unroll
  for (int kt = 0; kt < 8; ++kt) {
    int g = kt * 4 + qq;
    int pos = (g & ~7) | ((g & 7) ^ (lr & 7));
    short8 av[4];
#pragma unroll
    for (int ms = 0; ms < 4; ++ms)
      av[ms] = *(const short8*)(Abase + (wm + ms * 16 + lr) * 256 + pos * 8);
    short8 b0 = *(const short8*)(Ws + (wj + lr) * 256 + pos * 8);
    short8 b1 = *(const short8*)(Ws + (wj + 16 + lr) * 256 + pos * 8);
#pragma unroll
    for (int ms = 0; ms < 4; ++ms) {
      acc[ms][0] = __builtin_amdgcn_mfma_f32_16x16x32_bf16(av[ms], b0, acc[ms][0], 0, 0, 0);
      acc[ms][1] = __builtin_amdgcn_mfma_f32_16x16x32_bf16(av[ms], b1, acc[ms][1], 0, 0, 0);
    }
  }
}

// K|V projection. K out: per (b,h) chunk layout [nch32][2][32][8] (attn A-frag
// = contiguous lane-linear read). V out: [bh][d][n] XOR-swizzled on n.
__global__ __launch_bounds__(256) void gemm_kv_kernel(
    const u16* __restrict__ nodes_bf, const u16* __restrict__ Wkv,
    u16* __restrict__ Kbuf, u16* __restrict__ Vbuf) {
  __shared__ __attribute__((aligned(16))) u16 Ws[16384];
  int bx = blockIdx.x;
  int jt = bx & 7, mt = (bx >> 3) & 3, b = bx >> 5;
  f32x4 acc[4][2];
  proj_core(nodes_bf + (b * 512 + mt * 128) * 256, Wkv + jt * 64 * 256, Ws, acc);
  int t = threadIdx.x, lane = t & 63, w = t >> 6;
  int wm = (w & 1) * 64, wj = (w >> 1) * 32, qq = lane >> 4, lr = lane & 15;
  for (int ms = 0; ms < 4; ++ms)
    for (int fj = 0; fj < 2; ++fj) {
      int j = jt * 64 + wj + fj * 16 + lr;
      for (int r = 0; r < 4; ++r) {
        int n = mt * 128 + wm + ms * 16 + qq * 4 + r;
        u16 val = f2bf(acc[ms][fj][r]);
        if (j < 256) {
          int h = j >> 4, d = j & 15;
          Kbuf[(u32)(b * 16 + h) * 8192 + (u32)(n >> 5) * 512 +
               (u32)(d >> 3) * 256 + (u32)(n & 31) * 8 + (u32)(d & 7)] = val;
        } else {
          int o = j - 256, h = o >> 4, d = o & 15;
          u32 G = (u32)(n >> 3);
          u32 pos = (G & ~7u) | ((G & 7u) ^ ((u32)d & 7u));
          Vbuf[(u32)(b * 16 + h) * 8192 + (u32)d * 512 + pos * 8 + (u32)(n & 7)] = val;
        }
      }
    }
}

// Q projection -> Qbuf [bh][p][16], pre-scaled by 0.25*log2e, +load*wq_last.
__global__ __launch_bounds__(256) void gemm_q_kernel(
    const u16* __restrict__ last_bf, const u16* __restrict__ Wqm,
    const float* __restrict__ wq_last, const float* __restrict__ loadv,
    u16* __restrict__ Qbuf) {
  __shared__ __attribute__((aligned(16))) u16 Ws[16384];
  int bx = blockIdx.x;
  int jt = bx & 3, mt = (bx >> 2) & 3, b = bx >> 4;
  f32x4 acc[4][2];
  proj_core(last_bf + (b * 512 + mt * 128) * 256, Wqm + jt * 64 * 256, Ws, acc);
  int t = threadIdx.x, lane = t & 63, w = t >> 6;
  int wm = (w & 1) * 64, wj = (w >> 1) * 32, qq = lane >> 4, lr = lane & 15;
  for (int ms = 0; ms < 4; ++ms)
    for (int fj = 0; fj < 2; ++fj) {
      int o = jt * 64 + wj + fj * 16 + lr;
      float wql = wq_last[o];
      for (int r = 0; r < 4; ++r) {
        int p = mt * 128 + wm + ms * 16 + qq * 4 + r;
        float ld = loadv[b * 512 + p];
        float v = (acc[ms][fj][r] + ld * wql) * QSCALE;
        Qbuf[((b * 16 + (o >> 4)) * 512 + p) * 16 + (o & 15)] = f2bf(v);
      }
    }
}

// ---------------------------------------------------------------------------
// Attention: one (b,h, p-tile-of-128) per block; wave = 32 Q-rows.
// S^T = K*Q^T via mfma_32x32x16 (K=16==D). P relayout in registers
// (shfl_xor 32 + cndmask). exp2 path, no max-subtraction (|score| small).
// ---------------------------------------------------------------------------
__global__ __launch_bounds__(256) void attn_kernel(
    const u16* __restrict__ Qb, const u16* __restrict__ Kb,
    const u16* __restrict__ Vb, u16* __restrict__ Ob) {
  __shared__ __attribute__((aligned(16))) u16 Ks[8192];
  __shared__ __attribute__((aligned(16))) u16 Vt[8192];
  int bx = blockIdx.x;
  int pt = bx & 3, bh = bx >> 2;
  int t = threadIdx.x, lane = t & 63, w = t >> 6;
  int lo5 = lane & 31, hi = lane >> 5;
  int vd = lane & 15;
  for (int c = 0; c < 4; ++c) {
    __builtin_amdgcn_global_load_lds(AS1U(Kb + bh * 8192 + c * 2048 + t * 8),
                                     AS3U(Ks + c * 2048 + w * 512), 16, 0, 0);
    __builtin_amdgcn_global_load_lds(AS1U(Vb + bh * 8192 + c * 2048 + t * 8),
                                     AS3U(Vt + c * 2048 + w * 512), 16, 0, 0);
  }
  int p0 = pt * 128 + w * 32;
  short8 qf = *(const short8*)(Qb + bh * 8192 + (p0 + lo5) * 16 + hi * 8);
  __syncthreads();
  f32x16 oacc = {};
  float lsum = 0.f;
  for (int it = 0; it < 16; ++it) {
    short8 kf = *(const short8*)(Ks + it * 512 + lane * 8);
    f32x16 st = __builtin_amdgcn_mfma_f32_32x32x16_bf16(kf, qf, (f32x16){}, 0, 0, 0);
    float ev[16];
    float ls = 0.f;
#pragma unroll
    for (int r = 0; r < 16; ++r) ev[r] = __builtin_amdgcn_exp2f(st[r]);
#pragma unroll
    for (int r = 0; r < 16; ++r) ls += ev[r];
    lsum += ls;
    u32 pk[8], pd[8];
#pragma unroll
    for (int q = 0; q < 8; ++q) pk[q] = pack_bf(ev[2 * q], ev[2 * q + 1]);
#pragma unroll
    for (int q = 0; q < 8; ++q) pd[q] = (u32)__shfl_xor((int)pk[q], 32, 64);
    bool h1 = (hi != 0);
    u32x4 a1u = {h1 ? pd[2] : pk[0], h1 ? pd[3] : pk[1],
                 h1 ? pk[2] : pd[0], h1 ? pk[3] : pd[1]};
    u32x4 a2u = {h1 ? pd[6] : pk[4], h1 ? pd[7] : pk[5],
                 h1 ? pk[6] : pd[4], h1 ? pk[7] : pd[5]};
    short8 A1 = __builtin_bit_cast(short8, a1u);
    short8 A2 = __builtin_bit_cast(short8, a2u);
    int G1 = it * 4 + hi, G2 = G1 + 2;
    short8 v1 = *(const short8*)(Vt + vd * 512 + (((G1 & ~7) | ((G1 & 7) ^ (vd & 7)))) * 8);
    short8 v2 = *(const short8*)(Vt + vd * 512 + (((G2 & ~7) | ((G2 & 7) ^ (vd & 7)))) * 8);
    oacc = __builtin_amdgcn_mfma_f32_32x32x16_bf16(A1, v1, oacc, 0, 0, 0);
    oacc = __builtin_amdgcn_mfma_f32_32x32x16_bf16(A2, v2, oacc, 0, 0, 0);
  }
  lsum += __shfl_xor(lsum, 32, 64);
  float inv = __builtin_amdgcn_rcpf(lsum);
  float iv[16];
#pragma unroll
  for (int r = 0; r < 16; ++r) {
    int pl = (r & 3) + 8 * (r >> 2) + 4 * hi;
    iv[r] = __shfl(inv, pl, 64);
  }
  int b = bh >> 4, h = bh & 15;
  if (lo5 < 16) {
#pragma unroll
    for (int r = 0; r < 16; ++r) {
      int pl = (r & 3) + 8 * (r >> 2) + 4 * hi;
      u32 row = (u32)(b * 512 + p0 + pl);
      u32 k = (u32)(h * 16 + lo5);
      Ob[swz_off(row, k)] = f2bf(oacc[r] * iv[r]);
    }
  }
}

// C-projection: mh = (O @ Wc^T + bias)/16, written row-swizzled.
__global__ __launch_bounds__(256) void gemm_c_kernel(
    const u16* __restrict__ Obuf, const u16* __restrict__ Wcm,
    const float* __restrict__ Wcb, u16* __restrict__ mh_bf) {
  __shared__ __attribute__((aligned(16))) u16 Ws[16384];
  int bx = blockIdx.x;
  int jt = bx & 3, mt = (bx >> 2) & 3, b = bx >> 4;
  f32x4 acc[4][2];
  proj_core(Obuf + (b * 512 + mt * 128) * 256, Wcm + jt * 64 * 256, Ws, acc);
  int t = threadIdx.x, lane = t & 63, w = t >> 6;
  int wm = (w & 1) * 64, wj = (w >> 1) * 32, qq = lane >> 4, lr = lane & 15;
  for (int ms = 0; ms < 4; ++ms)
    for (int fj = 0; fj < 2; ++fj) {
      int e = jt * 64 + wj + fj * 16 + lr;
      float bias = Wcb[e];
      for (int r = 0; r < 4; ++r) {
        int p = mt * 128 + wm + ms * 16 + qq * 4 + r;
        mh_bf[swz_off((u32)(b * 512 + p), (u32)e)] = f2bf((acc[ms][fj][r] + bias) * 0.0625f);
      }
    }
}

// ---------------------------------------------------------------------------
// Fused score2 GEMM + topk(100 smallest) + penalty + tanh-clip + ninf +
// softmax. Block = 16 rows x 512 cols of one b. B-frags direct global->VGPR
// (L2-hot), double-buffered at nt granularity. Phase 2: cdist/ninf for all
// 4 rows prefetched pre-barrier; 4 binary searches run interleaved.
// __launch_bounds__(256,4): grid gives 4 blocks/CU regardless, so the
// 128-VGPR budget is free ILP headroom.
// ---------------------------------------------------------------------------
__global__ __launch_bounds__(256, 4) void s2_fused_kernel(
    const u16* __restrict__ mh_bf, const u16* __restrict__ nodes_bf,
    const float* __restrict__ cdist, const float* __restrict__ ninf,
    float* __restrict__ out) {
  __shared__ float lg[16][516];
  int bx = blockIdx.x;
  int ptile = bx & 31, b = bx >> 5;
  int t = threadIdx.x, lane = t & 63, w = t >> 6;
  int qq = lane >> 4, lr = lane & 15;
  // hoisted A-fragments (16 rows x 256 k) from swizzled global
  short8 afr[8];
  const u16* Abase = mh_bf + (u32)(b * 512 + ptile * 16) * 256;
#pragma unroll
  for (int kt = 0; kt < 8; ++kt) {
    int g = kt * 4 + qq;
    int pos = (g & ~7) | ((g & 7) ^ (lr & 7));
    afr[kt] = *(const short8*)(Abase + lr * 256 + pos * 8);
  }
  // GEMM: wave w owns cols [w*128, w*128+128), B direct from global.
  // Two named buffers, fully unrolled -> all indices static (no scratch).
  const u16* Bbase = nodes_bf + (u32)b * 512 * 256;
  short8 bva[8], bvb[8];
#define LOADB(dst, nt)                                                      \
  {                                                                         \
    _Pragma("unroll") for (int kt = 0; kt < 8; ++kt) {                      \
      int g = kt * 4 + qq;                                                  \
      int pos = (g & ~7) | ((g & 7) ^ (lr & 7));                            \
      dst[kt] = *(const short8*)(Bbase + ((nt)*16 + lr) * 256 + pos * 8);   \
    }                                                                       \
  }
  LOADB(bva, w * 8 + 0)
#pragma unroll
  for (int np = 0; np < 4; ++np) {
    int nte = w * 8 + np * 2;
    // prefetch odd buffer, compute even
    LOADB(bvb, nte + 1)
    f32x4 acc = {0.f, 0.f, 0.f, 0.f};
#pragma unroll
    for (int kt = 0; kt < 8; ++kt)
      acc = __builtin_amdgcn_mfma_f32_16x16x32_bf16(afr[kt], bva[kt], acc, 0, 0, 0);
#pragma unroll
    for (int r = 0; r < 4; ++r) lg[qq * 4 + r][(nte + 0) * 16 + lr] = acc[r];
    // prefetch next even buffer, compute odd
    if (np < 3) LOADB(bva, nte + 2)
    acc = (f32x4){0.f, 0.f, 0.f, 0.f};
#pragma unroll
    for (int kt = 0; kt < 8; ++kt)
      acc = __builtin_amdgcn_mfma_f32_16x16x32_bf16(afr[kt], bvb[kt], acc, 0, 0, 0);
#pragma unroll
    for (int r = 0; r < 4; ++r) lg[qq * 4 + r][(nte + 1) * 16 + lr] = acc[r];
  }
#undef LOADB
  // phase 2 inputs for this wave's 4 rows: issue before the barrier so
  // HBM latency hides under the slowest wave's GEMM + barrier drain.
  int row0 = w * 4;
  long grow = (long)b * 512 + ptile * 16 + row0;
  const u32* du = (const u32*)(cdist + grow * 512);
  const float* nrp = ninf + grow * 512;
  u32 u[4][8];
#pragma unroll
  for (int r = 0; r < 4; ++r)
#pragma unroll
    for (int i = 0; i < 8; ++i) u[r][i] = du[r * 512 + i * 64 + lane];
  float nf[4][8];
#pragma unroll
  for (int r = 0; r < 4; ++r)
#pragma unroll
    for (int i = 0; i < 8; ++i) nf[r][i] = nrp[r * 512 + i * 64 + lane];
  __syncthreads();
  // exact 100-smallest thresholds: 4 rows' radix binary searches in
  // lockstep (fixed 30 iters: 2^30 > 0x3F800001 guarantees lo==hi).
  u32 lo[4], hi_[4];
#pragma unroll
  for (int r = 0; r < 4; ++r) {
    lo[r] = 0u;
    hi_[r] = 0x3F800000u;  // uniform[0,1) upper bracket
  }
#pragma unroll 1
  for (int it = 0; it < 30; ++it) {
#pragma unroll
    for (int r = 0; r < 4; ++r) {
      u32 mid = lo[r] + ((hi_[r] - lo[r]) >> 1);
      int cnt = 0;
#pragma unroll
      for (int i = 0; i < 8; ++i) cnt += __popcll(__ballot(u[r][i] <= mid));
      bool ge = (cnt >= 100);
      hi_[r] = ge ? mid : hi_[r];
      lo[r] = ge ? lo[r] : mid + 1u;
    }
  }
  u64 lm = (1ull << lane) - 1ull;
#pragma unroll
  for (int r = 0; r < 4; ++r) {
    u32 T = lo[r];
    int cl = 0;
#pragma unroll
    for (int i = 0; i < 8; ++i) cl += __popcll(__ballot(u[r][i] < T));
    int quota = 100 - cl;
    int eqacc = 0;
    int row = row0 + r;
    float ex[8];
    float s = 0.f;
#pragma unroll
    for (int i = 0; i < 8; ++i) {
      u64 e = __ballot(u[r][i] == T);
      bool sel = (u[r][i] < T) ||
                 ((u[r][i] == T) && ((eqacc + __popcll(e & lm)) < quota));
      eqacc += __popcll(e);
      float dv = __builtin_bit_cast(float, u[r][i]);
      float x = lg[row][i * 64 + lane] + (sel ? -dv * INV_SQRT2 : 1.0f);
      float lgt = 10.0f * fast_tanh(x) + nf[r][i];
      ex[i] = __builtin_amdgcn_exp2f(lgt * LOG2E);
      s += ex[i];
    }
    for (int m = 1; m < 64; m <<= 1) s += __shfl_xor(s, m, 64);
    float inv = 1.0f / s;
    float* orow = out + (grow + r) * 512;
#pragma unroll
    for (int i = 0; i < 8; ++i) orow[i * 64 + lane] = ex[i] * inv;
  }
}

// ---------------------------------------------------------------------------
extern "C" void kernel_launch(void* const* d_in, const int* in_sizes, int n_in,
                              void* d_out, int out_size, void* d_ws, size_t ws_size,
                              hipStream_t stream) {
  const float* nodes = (const float*)d_in[0];
  const float* last  = (const float*)d_in[1];
  const float* loadv = (const float*)d_in[2];
  const float* cdist = (const float*)d_in[3];
  const float* ninf  = (const float*)d_in[6];
  const float* Wq    = (const float*)d_in[7];
  const float* Wk    = (const float*)d_in[8];
  const float* Wv    = (const float*)d_in[9];
  const float* Wc    = (const float*)d_in[10];
  const float* Wcb   = (const float*)d_in[11];

  char* ws = (char*)d_ws;
  u16* nodes_bf = (u16*)(ws + 0);
  u16* last_bf  = (u16*)(ws + 8388608);
  u16* Qbuf     = (u16*)(ws + 16777216);
  u16* Kbuf     = (u16*)(ws + 25165824);
  u16* Vbuf     = (u16*)(ws + 33554432);
  u16* Obuf     = (u16*)(ws + 41943040);
  u16* mh_bf    = (u16*)(ws + 50331648);
  u16* Wkv_bf   = (u16*)(ws + 58720256);
  u16* Wq_bf    = (u16*)(ws + 58982400);
  u16* Wc_bf    = (u16*)(ws + 59113472);
  float* wq_lc  = (float*)(ws + 59244544);

  float* out = (float*)d_out;

  convert_kernel<<<4225, 256, 0, stream>>>(nodes, last, Wk, Wv, Wq, Wc,
                                           nodes_bf, last_bf, Wkv_bf, Wq_bf,
                                           wq_lc, Wc_bf);
  gemm_kv_kernel<<<1024, 256, 0, stream>>>(nodes_bf, Wkv_bf, Kbuf, Vbuf);
  gemm_q_kernel<<<512, 256, 0, stream>>>(last_bf, Wq_bf, wq_lc, loadv, Qbuf);
  attn_kernel<<<2048, 256, 0, stream>>>(Qbuf, Kbuf, Vbuf, Obuf);
  gemm_c_kernel<<<512, 256, 0, stream>>>(Obuf, Wc_bf, Wcb, mh_bf);
  s2_fused_kernel<<<1024, 256, 0, stream>>>(mh_bf, nodes_bf, cdist, ninf, out);
}

// Round 2
// 279.328 us; speedup vs baseline: 1.0459x; 1.0459x over previous
//
#include <hip/hip_runtime.h>

// CVRP decoder v5, MI355X.
// Pipeline: convert -> gemm_kv -> gemm_q -> attn -> gemm_c -> s2a -> s2b.
// v5: s2 split. v4's fused-s2 register prefetch spilled (WRITE_SIZE +4MB of
// scratch) and the 33KB-LDS monolith caps residency at 4 blocks/CU with two
// long serial chains. Split instead:
//   s2a: logits GEMM via proj_core (mh_bf/nodes_bf already in proj layout),
//        fp32 logits -> workspace (reuses dead Qbuf..Obuf region, 32MB).
//   s2b: zero-LDS streaming post (1 wave = 1 row): search+penalty+tanh+
//        softmax, ~48 VGPR -> 8 waves/SIMD, 4096 blocks; BW-bound.

typedef unsigned short u16;
typedef unsigned int u32;
typedef unsigned long long u64;
typedef __attribute__((ext_vector_type(8))) short short8;
typedef __attribute__((ext_vector_type(4))) float f32x4;
typedef __attribute__((ext_vector_type(16))) float f32x16;
typedef __attribute__((ext_vector_type(4))) u32 u32x4;
typedef __attribute__((ext_vector_type(8))) u16 u16x8;

#define AS1U(p) ((const __attribute__((address_space(1))) u32*)(p))
#define AS3U(p) ((__attribute__((address_space(3))) u32*)(p))

#define QSCALE (0.25f * 1.44269504088896340736f)  // 1/sqrt(D) * log2(e)
#define LOG2E 1.44269504088896340736f
#define INV_SQRT2 0.70710678118654752440f

__device__ __forceinline__ u16 f2bf(float f) {
  u32 u = __builtin_bit_cast(u32, f);
  return (u16)((u + 0x7FFFu + ((u >> 16) & 1u)) >> 16);  // RNE
}

__device__ __forceinline__ u32 pack_bf(float a, float b) {
  u32 ua = __builtin_bit_cast(u32, a), ub = __builtin_bit_cast(u32, b);
  ua = ua + 0x7FFFu + ((ua >> 16) & 1u);
  ub = ub + 0x7FFFu + ((ub >> 16) & 1u);
  return __builtin_amdgcn_perm(ub, ua, 0x07060302u);
}

__device__ __forceinline__ u32 swz_off(u32 row, u32 k) {  // half-index
  u32 g = k >> 3;
  u32 pos = (g & ~7u) | ((g & 7u) ^ (row & 7u));
  return row * 256u + pos * 8u + (k & 7u);
}

__device__ __forceinline__ float fast_tanh(float x) {
  float e = __builtin_amdgcn_exp2f(x * (2.0f * LOG2E));
  return 1.0f - 2.0f * __builtin_amdgcn_rcpf(e + 1.0f);
}

// ---------------------------------------------------------------------------
// convert: fp32 -> bf16, one 8-element granule per thread, swizzled rows.
// ---------------------------------------------------------------------------
__global__ __launch_bounds__(256) void convert_kernel(
    const float* __restrict__ nodes, const float* __restrict__ last,
    const float* __restrict__ Wk, const float* __restrict__ Wv,
    const float* __restrict__ Wq, const float* __restrict__ Wc,
    u16* __restrict__ nodes_bf, u16* __restrict__ last_bf,
    u16* __restrict__ Wkv_bf, u16* __restrict__ Wq_bf,
    float* __restrict__ wq_last, u16* __restrict__ Wc_bf) {
  long i = (long)blockIdx.x * 256 + threadIdx.x;
  if (i < 524288) {  // nodes: 16384 rows x 32 granules
    u32 row = (u32)(i >> 5), g = (u32)(i & 31);
    const float4* s4 = (const float4*)nodes + i * 2;
    float4 v0 = s4[0], v1 = s4[1];
    u16x8 o = {f2bf(v0.x), f2bf(v0.y), f2bf(v0.z), f2bf(v0.w),
               f2bf(v1.x), f2bf(v1.y), f2bf(v1.z), f2bf(v1.w)};
    u32 pos = (g & ~7u) | ((g & 7u) ^ (row & 7u));
    *(u16x8*)(nodes_bf + row * 256 + pos * 8) = o;
  } else if (i < 1048576) {  // last
    long j = i - 524288;
    u32 row = (u32)(j >> 5), g = (u32)(j & 31);
    const float4* s4 = (const float4*)last + j * 2;
    float4 v0 = s4[0], v1 = s4[1];
    u16x8 o = {f2bf(v0.x), f2bf(v0.y), f2bf(v0.z), f2bf(v0.w),
               f2bf(v1.x), f2bf(v1.y), f2bf(v1.z), f2bf(v1.w)};
    u32 pos = (g & ~7u) | ((g & 7u) ^ (row & 7u));
    *(u16x8*)(last_bf + row * 256 + pos * 8) = o;
  } else if (i < 1064960) {  // Wkv: 512 rows (Wk | Wv)
    long j = i - 1048576;
    u32 row = (u32)(j >> 5), g = (u32)(j & 31);
    const float* src = (row < 256) ? (Wk + row * 256 + g * 8)
                                   : (Wv + (row - 256) * 256 + g * 8);
    u16x8 o;
    for (int q = 0; q < 8; q++) o[q] = f2bf(src[q]);
    u32 pos = (g & ~7u) | ((g & 7u) ^ (row & 7u));
    *(u16x8*)(Wkv_bf + row * 256 + pos * 8) = o;
  } else if (i < 1073152) {  // Wq main 256x256 (src stride 257)
    long j = i - 1064960;
    u32 row = (u32)(j >> 5), g = (u32)(j & 31);
    const float* src = Wq + row * 257 + g * 8;
    u16x8 o;
    for (int q = 0; q < 8; q++) o[q] = f2bf(src[q]);
    u32 pos = (g & ~7u) | ((g & 7u) ^ (row & 7u));
    *(u16x8*)(Wq_bf + row * 256 + pos * 8) = o;
  } else if (i < 1081344) {  // Wc 256x256
    long j = i - 1073152;
    u32 row = (u32)(j >> 5), g = (u32)(j & 31);
    const float* src = Wc + row * 256 + g * 8;
    u16x8 o;
    for (int q = 0; q < 8; q++) o[q] = f2bf(src[q]);
    u32 pos = (g & ~7u) | ((g & 7u) ^ (row & 7u));
    *(u16x8*)(Wc_bf + row * 256 + pos * 8) = o;
  } else if (i < 1081600) {  // Wq last column (fp32)
    long o = i - 1081344;
    wq_last[o] = Wq[o * 257 + 256];
  }
}

// ---------------------------------------------------------------------------
// proj core: block computes 128m x 64j, K=256. W j-tile (64x256, 32KB) staged
// once in LDS via DMA + single barrier; A-frags direct global->VGPR.
// Wave (2x2): 64m x 32j -> acc[4 msub][2 fj]. Zero in-loop barriers.
// ---------------------------------------------------------------------------
__device__ __forceinline__ void proj_core(
    const u16* __restrict__ Abase, const u16* __restrict__ Wbase,
    u16* Ws, f32x4 acc[4][2]) {
  const int t = threadIdx.x;
  const int lane = t & 63, w = t >> 6;
  const int wm = (w & 1) * 64, wj = (w >> 1) * 32;
  const int qq = lane >> 4, lr = lane & 15;
#pragma unroll
  for (int c = 0; c < 8; ++c)
    __builtin_amdgcn_global_load_lds(AS1U(Wbase + c * 2048 + t * 8),
                                     AS3U(Ws + c * 2048 + w * 512), 16, 0, 0);
#pragma unroll
  for (int ms = 0; ms < 4; ++ms)
    for (int fj = 0; fj < 2; ++fj) acc[ms][fj] = (f32x4){0.f, 0.f, 0.f, 0.f};
  __syncthreads();
#pragma unroll
  for (int kt = 0; kt < 8; ++kt) {
    int g = kt * 4 + qq;
    int pos = (g & ~7) | ((g & 7) ^ (lr & 7));
    short8 av[4];
#pragma unroll
    for (int ms = 0; ms < 4; ++ms)
      av[ms] = *(const short8*)(Abase + (wm + ms * 16 + lr) * 256 + pos * 8);
    short8 b0 = *(const short8*)(Ws + (wj + lr) * 256 + pos * 8);
    short8 b1 = *(const short8*)(Ws + (wj + 16 + lr) * 256 + pos * 8);
#pragma unroll
    for (int ms = 0; ms < 4; ++ms) {
      acc[ms][0] = __builtin_amdgcn_mfma_f32_16x16x32_bf16(av[ms], b0, acc[ms][0], 0, 0, 0);
      acc[ms][1] = __builtin_amdgcn_mfma_f32_16x16x32_bf16(av[ms], b1, acc[ms][1], 0, 0, 0);
    }
  }
}

// K|V projection. K out: per (b,h) chunk layout [nch32][2][32][8] (attn A-frag
// = contiguous lane-linear read). V out: [bh][d][n] XOR-swizzled on n.
__global__ __launch_bounds__(256) void gemm_kv_kernel(
    const u16* __restrict__ nodes_bf, const u16* __restrict__ Wkv,
    u16* __restrict__ Kbuf, u16* __restrict__ Vbuf) {
  __shared__ __attribute__((aligned(16))) u16 Ws[16384];
  int bx = blockIdx.x;
  int jt = bx & 7, mt = (bx >> 3) & 3, b = bx >> 5;
  f32x4 acc[4][2];
  proj_core(nodes_bf + (b * 512 + mt * 128) * 256, Wkv + jt * 64 * 256, Ws, acc);
  int t = threadIdx.x, lane = t & 63, w = t >> 6;
  int wm = (w & 1) * 64, wj = (w >> 1) * 32, qq = lane >> 4, lr = lane & 15;
  for (int ms = 0; ms < 4; ++ms)
    for (int fj = 0; fj < 2; ++fj) {
      int j = jt * 64 + wj + fj * 16 + lr;
      for (int r = 0; r < 4; ++r) {
        int n = mt * 128 + wm + ms * 16 + qq * 4 + r;
        u16 val = f2bf(acc[ms][fj][r]);
        if (j < 256) {
          int h = j >> 4, d = j & 15;
          Kbuf[(u32)(b * 16 + h) * 8192 + (u32)(n >> 5) * 512 +
               (u32)(d >> 3) * 256 + (u32)(n & 31) * 8 + (u32)(d & 7)] = val;
        } else {
          int o = j - 256, h = o >> 4, d = o & 15;
          u32 G = (u32)(n >> 3);
          u32 pos = (G & ~7u) | ((G & 7u) ^ ((u32)d & 7u));
          Vbuf[(u32)(b * 16 + h) * 8192 + (u32)d * 512 + pos * 8 + (u32)(n & 7)] = val;
        }
      }
    }
}

// Q projection -> Qbuf [bh][p][16], pre-scaled by 0.25*log2e, +load*wq_last.
__global__ __launch_bounds__(256) void gemm_q_kernel(
    const u16* __restrict__ last_bf, const u16* __restrict__ Wqm,
    const float* __restrict__ wq_last, const float* __restrict__ loadv,
    u16* __restrict__ Qbuf) {
  __shared__ __attribute__((aligned(16))) u16 Ws[16384];
  int bx = blockIdx.x;
  int jt = bx & 3, mt = (bx >> 2) & 3, b = bx >> 4;
  f32x4 acc[4][2];
  proj_core(last_bf + (b * 512 + mt * 128) * 256, Wqm + jt * 64 * 256, Ws, acc);
  int t = threadIdx.x, lane = t & 63, w = t >> 6;
  int wm = (w & 1) * 64, wj = (w >> 1) * 32, qq = lane >> 4, lr = lane & 15;
  for (int ms = 0; ms < 4; ++ms)
    for (int fj = 0; fj < 2; ++fj) {
      int o = jt * 64 + wj + fj * 16 + lr;
      float wql = wq_last[o];
      for (int r = 0; r < 4; ++r) {
        int p = mt * 128 + wm + ms * 16 + qq * 4 + r;
        float ld = loadv[b * 512 + p];
        float v = (acc[ms][fj][r] + ld * wql) * QSCALE;
        Qbuf[((b * 16 + (o >> 4)) * 512 + p) * 16 + (o & 15)] = f2bf(v);
      }
    }
}

// ---------------------------------------------------------------------------
// Attention: one (b,h, p-tile-of-128) per block; wave = 32 Q-rows.
// S^T = K*Q^T via mfma_32x32x16 (K=16==D). P relayout in registers
// (shfl_xor 32 + cndmask). exp2 path, no max-subtraction (|score| small).
// ---------------------------------------------------------------------------
__global__ __launch_bounds__(256) void attn_kernel(
    const u16* __restrict__ Qb, const u16* __restrict__ Kb,
    const u16* __restrict__ Vb, u16* __restrict__ Ob) {
  __shared__ __attribute__((aligned(16))) u16 Ks[8192];
  __shared__ __attribute__((aligned(16))) u16 Vt[8192];
  int bx = blockIdx.x;
  int pt = bx & 3, bh = bx >> 2;
  int t = threadIdx.x, lane = t & 63, w = t >> 6;
  int lo5 = lane & 31, hi = lane >> 5;
  int vd = lane & 15;
  for (int c = 0; c < 4; ++c) {
    __builtin_amdgcn_global_load_lds(AS1U(Kb + bh * 8192 + c * 2048 + t * 8),
                                     AS3U(Ks + c * 2048 + w * 512), 16, 0, 0);
    __builtin_amdgcn_global_load_lds(AS1U(Vb + bh * 8192 + c * 2048 + t * 8),
                                     AS3U(Vt + c * 2048 + w * 512), 16, 0, 0);
  }
  int p0 = pt * 128 + w * 32;
  short8 qf = *(const short8*)(Qb + bh * 8192 + (p0 + lo5) * 16 + hi * 8);
  __syncthreads();
  f32x16 oacc = {};
  float lsum = 0.f;
  for (int it = 0; it < 16; ++it) {
    short8 kf = *(const short8*)(Ks + it * 512 + lane * 8);
    f32x16 st = __builtin_amdgcn_mfma_f32_32x32x16_bf16(kf, qf, (f32x16){}, 0, 0, 0);
    float ev[16];
    float ls = 0.f;
#pragma unroll
    for (int r = 0; r < 16; ++r) ev[r] = __builtin_amdgcn_exp2f(st[r]);
#pragma unroll
    for (int r = 0; r < 16; ++r) ls += ev[r];
    lsum += ls;
    u32 pk[8], pd[8];
#pragma unroll
    for (int q = 0; q < 8; ++q) pk[q] = pack_bf(ev[2 * q], ev[2 * q + 1]);
#pragma unroll
    for (int q = 0; q < 8; ++q) pd[q] = (u32)__shfl_xor((int)pk[q], 32, 64);
    bool h1 = (hi != 0);
    u32x4 a1u = {h1 ? pd[2] : pk[0], h1 ? pd[3] : pk[1],
                 h1 ? pk[2] : pd[0], h1 ? pk[3] : pd[1]};
    u32x4 a2u = {h1 ? pd[6] : pk[4], h1 ? pd[7] : pk[5],
                 h1 ? pk[6] : pd[4], h1 ? pk[7] : pd[5]};
    short8 A1 = __builtin_bit_cast(short8, a1u);
    short8 A2 = __builtin_bit_cast(short8, a2u);
    int G1 = it * 4 + hi, G2 = G1 + 2;
    short8 v1 = *(const short8*)(Vt + vd * 512 + (((G1 & ~7) | ((G1 & 7) ^ (vd & 7)))) * 8);
    short8 v2 = *(const short8*)(Vt + vd * 512 + (((G2 & ~7) | ((G2 & 7) ^ (vd & 7)))) * 8);
    oacc = __builtin_amdgcn_mfma_f32_32x32x16_bf16(A1, v1, oacc, 0, 0, 0);
    oacc = __builtin_amdgcn_mfma_f32_32x32x16_bf16(A2, v2, oacc, 0, 0, 0);
  }
  lsum += __shfl_xor(lsum, 32, 64);
  float inv = __builtin_amdgcn_rcpf(lsum);
  float iv[16];
#pragma unroll
  for (int r = 0; r < 16; ++r) {
    int pl = (r & 3) + 8 * (r >> 2) + 4 * hi;
    iv[r] = __shfl(inv, pl, 64);
  }
  int b = bh >> 4, h = bh & 15;
  if (lo5 < 16) {
#pragma unroll
    for (int r = 0; r < 16; ++r) {
      int pl = (r & 3) + 8 * (r >> 2) + 4 * hi;
      u32 row = (u32)(b * 512 + p0 + pl);
      u32 k = (u32)(h * 16 + lo5);
      Ob[swz_off(row, k)] = f2bf(oacc[r] * iv[r]);
    }
  }
}

// C-projection: mh = (O @ Wc^T + bias)/16, written row-swizzled.
__global__ __launch_bounds__(256) void gemm_c_kernel(
    const u16* __restrict__ Obuf, const u16* __restrict__ Wcm,
    const float* __restrict__ Wcb, u16* __restrict__ mh_bf) {
  __shared__ __attribute__((aligned(16))) u16 Ws[16384];
  int bx = blockIdx.x;
  int jt = bx & 3, mt = (bx >> 2) & 3, b = bx >> 4;
  f32x4 acc[4][2];
  proj_core(Obuf + (b * 512 + mt * 128) * 256, Wcm + jt * 64 * 256, Ws, acc);
  int t = threadIdx.x, lane = t & 63, w = t >> 6;
  int wm = (w & 1) * 64, wj = (w >> 1) * 32, qq = lane >> 4, lr = lane & 15;
  for (int ms = 0; ms < 4; ++ms)
    for (int fj = 0; fj < 2; ++fj) {
      int e = jt * 64 + wj + fj * 16 + lr;
      float bias = Wcb[e];
      for (int r = 0; r < 4; ++r) {
        int p = mt * 128 + wm + ms * 16 + qq * 4 + r;
        mh_bf[swz_off((u32)(b * 512 + p), (u32)e)] = f2bf((acc[ms][fj][r] + bias) * 0.0625f);
      }
    }
}

// ---------------------------------------------------------------------------
// s2a: logits GEMM. logits[b][p][n] = (mh/16) . nodes  (fp32, 32MB in ws).
// Same proj_core structure: A = mh_bf (row-swizzled), W-tile = 64 node rows
// (row-swizzled, staged to LDS). Block = 128p x 64n; grid 32b x 4mt x 8jt.
// ---------------------------------------------------------------------------
__global__ __launch_bounds__(256) void s2a_gemm_kernel(
    const u16* __restrict__ mh_bf, const u16* __restrict__ nodes_bf,
    float* __restrict__ lgbuf) {
  __shared__ __attribute__((aligned(16))) u16 Ws[16384];
  int bx = blockIdx.x;
  int jt = bx & 7, mt = (bx >> 3) & 3, b = bx >> 5;
  f32x4 acc[4][2];
  proj_core(mh_bf + (b * 512 + mt * 128) * 256,
            nodes_bf + ((u32)b * 512 + jt * 64) * 256, Ws, acc);
  int t = threadIdx.x, lane = t & 63, w = t >> 6;
  int wm = (w & 1) * 64, wj = (w >> 1) * 32, qq = lane >> 4, lr = lane & 15;
  for (int ms = 0; ms < 4; ++ms)
    for (int fj = 0; fj < 2; ++fj)
      for (int r = 0; r < 4; ++r) {
        int p = mt * 128 + wm + ms * 16 + qq * 4 + r;
        int n = jt * 64 + wj + fj * 16 + lr;
        lgbuf[((u32)b * 512 + p) * 512 + (u32)n] = acc[ms][fj][r];
      }
}

// ---------------------------------------------------------------------------
// s2b: streaming post. One wave per row (512 cols): exact 100-smallest
// binary search on cdist bits + tie-break quota (index order identical to
// reference top_k), penalty, tanh-clip, ninf, softmax, write. Zero LDS,
// ~48 VGPR -> 8 waves/SIMD; grid 4096 blocks; BW-bound.
// ---------------------------------------------------------------------------
__global__ __launch_bounds__(256) void s2b_kernel(
    const float* __restrict__ lgbuf, const float* __restrict__ cdist,
    const float* __restrict__ ninf, float* __restrict__ out) {
  int t = threadIdx.x, lane = t & 63, w = t >> 6;
  long grow = (long)blockIdx.x * 4 + w;  // 0..16383 = b*512+p
  const u32* du = (const u32*)(cdist + grow * 512);
  const float* lgr = lgbuf + grow * 512;
  u32 u[8];
  float lgv[8];
#pragma unroll
  for (int i = 0; i < 8; ++i) u[i] = du[i * 64 + lane];
#pragma unroll
  for (int i = 0; i < 8; ++i) lgv[i] = lgr[i * 64 + lane];
  // exact 100-smallest threshold: radix binary search on fp32 bits
  u32 lo = 0u, hi_ = 0x3F800000u;  // uniform[0,1) upper bracket
  while (lo < hi_) {
    u32 mid = lo + ((hi_ - lo) >> 1);
    int cnt = 0;
#pragma unroll
    for (int i = 0; i < 8; ++i) cnt += __popcll(__ballot(u[i] <= mid));
    if (cnt >= 100) hi_ = mid; else lo = mid + 1;
  }
  u32 T = lo;
  int cl = 0;
#pragma unroll
  for (int i = 0; i < 8; ++i) cl += __popcll(__ballot(u[i] < T));
  int quota = 100 - cl;
  u64 lm = (1ull << lane) - 1ull;
  int eqacc = 0;
  const float* nr = ninf + grow * 512;
  float ex[8];
  float s = 0.f;
#pragma unroll
  for (int i = 0; i < 8; ++i) {
    u64 e = __ballot(u[i] == T);
    bool sel = (u[i] < T) || ((u[i] == T) && ((eqacc + __popcll(e & lm)) < quota));
    eqacc += __popcll(e);
    float dv = __builtin_bit_cast(float, u[i]);
    float x = lgv[i] + (sel ? -dv * INV_SQRT2 : 1.0f);
    float lgt = 10.0f * fast_tanh(x) + nr[i * 64 + lane];
    ex[i] = __builtin_amdgcn_exp2f(lgt * LOG2E);
    s += ex[i];
  }
  for (int m = 1; m < 64; m <<= 1) s += __shfl_xor(s, m, 64);
  float inv = 1.0f / s;
  float* orow = out + grow * 512;
#pragma unroll
  for (int i = 0; i < 8; ++i) orow[i * 64 + lane] = ex[i] * inv;
}

// ---------------------------------------------------------------------------
extern "C" void kernel_launch(void* const* d_in, const int* in_sizes, int n_in,
                              void* d_out, int out_size, void* d_ws, size_t ws_size,
                              hipStream_t stream) {
  const float* nodes = (const float*)d_in[0];
  const float* last  = (const float*)d_in[1];
  const float* loadv = (const float*)d_in[2];
  const float* cdist = (const float*)d_in[3];
  const float* ninf  = (const float*)d_in[6];
  const float* Wq    = (const float*)d_in[7];
  const float* Wk    = (const float*)d_in[8];
  const float* Wv    = (const float*)d_in[9];
  const float* Wc    = (const float*)d_in[10];
  const float* Wcb   = (const float*)d_in[11];

  char* ws = (char*)d_ws;
  u16* nodes_bf = (u16*)(ws + 0);
  u16* last_bf  = (u16*)(ws + 8388608);
  u16* Qbuf     = (u16*)(ws + 16777216);
  u16* Kbuf     = (u16*)(ws + 25165824);
  u16* Vbuf     = (u16*)(ws + 33554432);
  u16* Obuf     = (u16*)(ws + 41943040);
  u16* mh_bf    = (u16*)(ws + 50331648);
  u16* Wkv_bf   = (u16*)(ws + 58720256);
  u16* Wq_bf    = (u16*)(ws + 58982400);
  u16* Wc_bf    = (u16*)(ws + 59113472);
  float* wq_lc  = (float*)(ws + 59244544);
  // fp32 logits (32MB) reuse the dead Qbuf..Obuf region (s2a runs after
  // attn/gemm_c have consumed them).
  float* lgbuf  = (float*)(ws + 16777216);

  float* out = (float*)d_out;

  convert_kernel<<<4225, 256, 0, stream>>>(nodes, last, Wk, Wv, Wq, Wc,
                                           nodes_bf, last_bf, Wkv_bf, Wq_bf,
                                           wq_lc, Wc_bf);
  gemm_kv_kernel<<<1024, 256, 0, stream>>>(nodes_bf, Wkv_bf, Kbuf, Vbuf);
  gemm_q_kernel<<<512, 256, 0, stream>>>(last_bf, Wq_bf, wq_lc, loadv, Qbuf);
  attn_kernel<<<2048, 256, 0, stream>>>(Qbuf, Kbuf, Vbuf, Obuf);
  gemm_c_kernel<<<512, 256, 0, stream>>>(Obuf, Wc_bf, Wcb, mh_bf);
  s2a_gemm_kernel<<<1024, 256, 0, stream>>>(mh_bf, nodes_bf, lgbuf);
  s2b_kernel<<<4096, 256, 0, stream>>>(lgbuf, cdist, ninf, out);
}

// Round 3
// 267.798 us; speedup vs baseline: 1.0909x; 1.0431x over previous
//
#include <hip/hip_runtime.h>

// CVRP decoder v6, MI355X.
// Pipeline: convert -> gemm_kv -> gemm_q -> attn -> gemm_c -> s2a -> s2b.
// v6: attn VALU cut (T12). rocprof r2: attn VALUBusy 73%, MfmaUtil 10% ->
// VALU-bound on the P repack (pack_bf x8 = 40 ops + 8 ds_bpermute shfl +
// 8 cndmask per K-tile). Replace with 8x v_cvt_pk_bf16_f32 (1 op, RNE) +
// 4x v_permlane32_swap_b32 (new_a=[a.lo,b.lo], new_b=[a.hi,b.hi] exactly
// reproduces the h1?pd:pk construction). ~80 -> ~44 VALU ops/iter, zero
// in-loop DS shuffles.

typedef unsigned short u16;
typedef unsigned int u32;
typedef unsigned long long u64;
typedef __attribute__((ext_vector_type(8))) short short8;
typedef __attribute__((ext_vector_type(4))) float f32x4;
typedef __attribute__((ext_vector_type(16))) float f32x16;
typedef __attribute__((ext_vector_type(4))) u32 u32x4;
typedef __attribute__((ext_vector_type(8))) u16 u16x8;

#define AS1U(p) ((const __attribute__((address_space(1))) u32*)(p))
#define AS3U(p) ((__attribute__((address_space(3))) u32*)(p))

#define QSCALE (0.25f * 1.44269504088896340736f)  // 1/sqrt(D) * log2(e)
#define LOG2E 1.44269504088896340736f
#define INV_SQRT2 0.70710678118654752440f

__device__ __forceinline__ u16 f2bf(float f) {
  u32 u = __builtin_bit_cast(u32, f);
  return (u16)((u + 0x7FFFu + ((u >> 16) & 1u)) >> 16);  // RNE
}

__device__ __forceinline__ u32 cvt_pk_bf16(float a, float b) {
  u32 r;
  asm("v_cvt_pk_bf16_f32 %0, %1, %2" : "=v"(r) : "v"(a), "v"(b));
  return r;  // lo = bf16(a), hi = bf16(b), RNE
}

__device__ __forceinline__ u32 swz_off(u32 row, u32 k) {  // half-index
  u32 g = k >> 3;
  u32 pos = (g & ~7u) | ((g & 7u) ^ (row & 7u));
  return row * 256u + pos * 8u + (k & 7u);
}

__device__ __forceinline__ float fast_tanh(float x) {
  float e = __builtin_amdgcn_exp2f(x * (2.0f * LOG2E));
  return 1.0f - 2.0f * __builtin_amdgcn_rcpf(e + 1.0f);
}

// ---------------------------------------------------------------------------
// convert: fp32 -> bf16, one 8-element granule per thread, swizzled rows.
// ---------------------------------------------------------------------------
__global__ __launch_bounds__(256) void convert_kernel(
    const float* __restrict__ nodes, const float* __restrict__ last,
    const float* __restrict__ Wk, const float* __restrict__ Wv,
    const float* __restrict__ Wq, const float* __restrict__ Wc,
    u16* __restrict__ nodes_bf, u16* __restrict__ last_bf,
    u16* __restrict__ Wkv_bf, u16* __restrict__ Wq_bf,
    float* __restrict__ wq_last, u16* __restrict__ Wc_bf) {
  long i = (long)blockIdx.x * 256 + threadIdx.x;
  if (i < 524288) {  // nodes: 16384 rows x 32 granules
    u32 row = (u32)(i >> 5), g = (u32)(i & 31);
    const float4* s4 = (const float4*)nodes + i * 2;
    float4 v0 = s4[0], v1 = s4[1];
    u16x8 o = {f2bf(v0.x), f2bf(v0.y), f2bf(v0.z), f2bf(v0.w),
               f2bf(v1.x), f2bf(v1.y), f2bf(v1.z), f2bf(v1.w)};
    u32 pos = (g & ~7u) | ((g & 7u) ^ (row & 7u));
    *(u16x8*)(nodes_bf + row * 256 + pos * 8) = o;
  } else if (i < 1048576) {  // last
    long j = i - 524288;
    u32 row = (u32)(j >> 5), g = (u32)(j & 31);
    const float4* s4 = (const float4*)last + j * 2;
    float4 v0 = s4[0], v1 = s4[1];
    u16x8 o = {f2bf(v0.x), f2bf(v0.y), f2bf(v0.z), f2bf(v0.w),
               f2bf(v1.x), f2bf(v1.y), f2bf(v1.z), f2bf(v1.w)};
    u32 pos = (g & ~7u) | ((g & 7u) ^ (row & 7u));
    *(u16x8*)(last_bf + row * 256 + pos * 8) = o;
  } else if (i < 1064960) {  // Wkv: 512 rows (Wk | Wv)
    long j = i - 1048576;
    u32 row = (u32)(j >> 5), g = (u32)(j & 31);
    const float* src = (row < 256) ? (Wk + row * 256 + g * 8)
                                   : (Wv + (row - 256) * 256 + g * 8);
    u16x8 o;
    for (int q = 0; q < 8; q++) o[q] = f2bf(src[q]);
    u32 pos = (g & ~7u) | ((g & 7u) ^ (row & 7u));
    *(u16x8*)(Wkv_bf + row * 256 + pos * 8) = o;
  } else if (i < 1073152) {  // Wq main 256x256 (src stride 257)
    long j = i - 1064960;
    u32 row = (u32)(j >> 5), g = (u32)(j & 31);
    const float* src = Wq + row * 257 + g * 8;
    u16x8 o;
    for (int q = 0; q < 8; q++) o[q] = f2bf(src[q]);
    u32 pos = (g & ~7u) | ((g & 7u) ^ (row & 7u));
    *(u16x8*)(Wq_bf + row * 256 + pos * 8) = o;
  } else if (i < 1081344) {  // Wc 256x256
    long j = i - 1073152;
    u32 row = (u32)(j >> 5), g = (u32)(j & 31);
    const float* src = Wc + row * 256 + g * 8;
    u16x8 o;
    for (int q = 0; q < 8; q++) o[q] = f2bf(src[q]);
    u32 pos = (g & ~7u) | ((g & 7u) ^ (row & 7u));
    *(u16x8*)(Wc_bf + row * 256 + pos * 8) = o;
  } else if (i < 1081600) {  // Wq last column (fp32)
    long o = i - 1081344;
    wq_last[o] = Wq[o * 257 + 256];
  }
}

// ---------------------------------------------------------------------------
// proj core: block computes 128m x 64j, K=256. W j-tile (64x256, 32KB) staged
// once in LDS via DMA + single barrier; A-frags direct global->VGPR.
// Wave (2x2): 64m x 32j -> acc[4 msub][2 fj]. Zero in-loop barriers.
// ---------------------------------------------------------------------------
__device__ __forceinline__ void proj_core(
    const u16* __restrict__ Abase, const u16* __restrict__ Wbase,
    u16* Ws, f32x4 acc[4][2]) {
  const int t = threadIdx.x;
  const int lane = t & 63, w = t >> 6;
  const int wm = (w & 1) * 64, wj = (w >> 1) * 32;
  const int qq = lane >> 4, lr = lane & 15;
#pragma unroll
  for (int c = 0; c < 8; ++c)
    __builtin_amdgcn_global_load_lds(AS1U(Wbase + c * 2048 + t * 8),
                                     AS3U(Ws + c * 2048 + w * 512), 16, 0, 0);
#pragma unroll
  for (int ms = 0; ms < 4; ++ms)
    for (int fj = 0; fj < 2; ++fj) acc[ms][fj] = (f32x4){0.f, 0.f, 0.f, 0.f};
  __syncthreads();
#pragma unroll
  for (int kt = 0; kt < 8; ++kt) {
    int g = kt * 4 + qq;
    int pos = (g & ~7) | ((g & 7) ^ (lr & 7));
    short8 av[4];
#pragma unroll
    for (int ms = 0; ms < 4; ++ms)
      av[ms] = *(const short8*)(Abase + (wm + ms * 16 + lr) * 256 + pos * 8);
    short8 b0 = *(const short8*)(Ws + (wj + lr) * 256 + pos * 8);
    short8 b1 = *(const short8*)(Ws + (wj + 16 + lr) * 256 + pos * 8);
#pragma unroll
    for (int ms = 0; ms < 4; ++ms) {
      acc[ms][0] = __builtin_amdgcn_mfma_f32_16x16x32_bf16(av[ms], b0, acc[ms][0], 0, 0, 0);
      acc[ms][1] = __builtin_amdgcn_mfma_f32_16x16x32_bf16(av[ms], b1, acc[ms][1], 0, 0, 0);
    }
  }
}

// K|V projection. K out: per (b,h) chunk layout [nch32][2][32][8] (attn A-frag
// = contiguous lane-linear read). V out: [bh][d][n] XOR-swizzled on n.
__global__ __launch_bounds__(256) void gemm_kv_kernel(
    const u16* __restrict__ nodes_bf, const u16* __restrict__ Wkv,
    u16* __restrict__ Kbuf, u16* __restrict__ Vbuf) {
  __shared__ __attribute__((aligned(16))) u16 Ws[16384];
  int bx = blockIdx.x;
  int jt = bx & 7, mt = (bx >> 3) & 3, b = bx >> 5;
  f32x4 acc[4][2];
  proj_core(nodes_bf + (b * 512 + mt * 128) * 256, Wkv + jt * 64 * 256, Ws, acc);
  int t = threadIdx.x, lane = t & 63, w = t >> 6;
  int wm = (w & 1) * 64, wj = (w >> 1) * 32, qq = lane >> 4, lr = lane & 15;
  for (int ms = 0; ms < 4; ++ms)
    for (int fj = 0; fj < 2; ++fj) {
      int j = jt * 64 + wj + fj * 16 + lr;
      for (int r = 0; r < 4; ++r) {
        int n = mt * 128 + wm + ms * 16 + qq * 4 + r;
        u16 val = f2bf(acc[ms][fj][r]);
        if (j < 256) {
          int h = j >> 4, d = j & 15;
          Kbuf[(u32)(b * 16 + h) * 8192 + (u32)(n >> 5) * 512 +
               (u32)(d >> 3) * 256 + (u32)(n & 31) * 8 + (u32)(d & 7)] = val;
        } else {
          int o = j - 256, h = o >> 4, d = o & 15;
          u32 G = (u32)(n >> 3);
          u32 pos = (G & ~7u) | ((G & 7u) ^ ((u32)d & 7u));
          Vbuf[(u32)(b * 16 + h) * 8192 + (u32)d * 512 + pos * 8 + (u32)(n & 7)] = val;
        }
      }
    }
}

// Q projection -> Qbuf [bh][p][16], pre-scaled by 0.25*log2e, +load*wq_last.
__global__ __launch_bounds__(256) void gemm_q_kernel(
    const u16* __restrict__ last_bf, const u16* __restrict__ Wqm,
    const float* __restrict__ wq_last, const float* __restrict__ loadv,
    u16* __restrict__ Qbuf) {
  __shared__ __attribute__((aligned(16))) u16 Ws[16384];
  int bx = blockIdx.x;
  int jt = bx & 3, mt = (bx >> 2) & 3, b = bx >> 4;
  f32x4 acc[4][2];
  proj_core(last_bf + (b * 512 + mt * 128) * 256, Wqm + jt * 64 * 256, Ws, acc);
  int t = threadIdx.x, lane = t & 63, w = t >> 6;
  int wm = (w & 1) * 64, wj = (w >> 1) * 32, qq = lane >> 4, lr = lane & 15;
  for (int ms = 0; ms < 4; ++ms)
    for (int fj = 0; fj < 2; ++fj) {
      int o = jt * 64 + wj + fj * 16 + lr;
      float wql = wq_last[o];
      for (int r = 0; r < 4; ++r) {
        int p = mt * 128 + wm + ms * 16 + qq * 4 + r;
        float ld = loadv[b * 512 + p];
        float v = (acc[ms][fj][r] + ld * wql) * QSCALE;
        Qbuf[((b * 16 + (o >> 4)) * 512 + p) * 16 + (o & 15)] = f2bf(v);
      }
    }
}

// ---------------------------------------------------------------------------
// Attention: one (b,h, p-tile-of-128) per block; wave = 32 Q-rows.
// S^T = K*Q^T via mfma_32x32x16 (K=16==D). P relayout in registers via
// v_cvt_pk_bf16_f32 + v_permlane32_swap_b32 (T12). exp2 path, no
// max-subtraction (|score| small).
// ---------------------------------------------------------------------------
__global__ __launch_bounds__(256) void attn_kernel(
    const u16* __restrict__ Qb, const u16* __restrict__ Kb,
    const u16* __restrict__ Vb, u16* __restrict__ Ob) {
  __shared__ __attribute__((aligned(16))) u16 Ks[8192];
  __shared__ __attribute__((aligned(16))) u16 Vt[8192];
  int bx = blockIdx.x;
  int pt = bx & 3, bh = bx >> 2;
  int t = threadIdx.x, lane = t & 63, w = t >> 6;
  int lo5 = lane & 31, hi = lane >> 5;
  int vd = lane & 15;
  for (int c = 0; c < 4; ++c) {
    __builtin_amdgcn_global_load_lds(AS1U(Kb + bh * 8192 + c * 2048 + t * 8),
                                     AS3U(Ks + c * 2048 + w * 512), 16, 0, 0);
    __builtin_amdgcn_global_load_lds(AS1U(Vb + bh * 8192 + c * 2048 + t * 8),
                                     AS3U(Vt + c * 2048 + w * 512), 16, 0, 0);
  }
  int p0 = pt * 128 + w * 32;
  short8 qf = *(const short8*)(Qb + bh * 8192 + (p0 + lo5) * 16 + hi * 8);
  __syncthreads();
  f32x16 oacc = {};
  float lsum = 0.f;
  for (int it = 0; it < 16; ++it) {
    short8 kf = *(const short8*)(Ks + it * 512 + lane * 8);
    f32x16 st = __builtin_amdgcn_mfma_f32_32x32x16_bf16(kf, qf, (f32x16){}, 0, 0, 0);
    float ev[16];
    float ls = 0.f;
#pragma unroll
    for (int r = 0; r < 16; ++r) ev[r] = __builtin_amdgcn_exp2f(st[r]);
#pragma unroll
    for (int r = 0; r < 16; ++r) ls += ev[r];
    lsum += ls;
    // P -> bf16 repack + cross-half exchange, fully in-register (T12).
    // pk_q = {bf(ev[2q]), bf(ev[2q+1])}; permlane32_swap(a,b) yields
    // new_a = [a.lanes0-31, b.lanes0-31], new_b = [a.lanes32-63, b.lanes32-63]
    // == the previous (h1 ? pd : pk) cndmask construction.
    u32 q0 = cvt_pk_bf16(ev[0], ev[1]);
    u32 q1 = cvt_pk_bf16(ev[2], ev[3]);
    u32 q2 = cvt_pk_bf16(ev[4], ev[5]);
    u32 q3 = cvt_pk_bf16(ev[6], ev[7]);
    u32 q4 = cvt_pk_bf16(ev[8], ev[9]);
    u32 q5 = cvt_pk_bf16(ev[10], ev[11]);
    u32 q6 = cvt_pk_bf16(ev[12], ev[13]);
    u32 q7 = cvt_pk_bf16(ev[14], ev[15]);
    asm("v_permlane32_swap_b32 %0, %1" : "+v"(q0), "+v"(q2));
    asm("v_permlane32_swap_b32 %0, %1" : "+v"(q1), "+v"(q3));
    asm("v_permlane32_swap_b32 %0, %1" : "+v"(q4), "+v"(q6));
    asm("v_permlane32_swap_b32 %0, %1" : "+v"(q5), "+v"(q7));
    u32x4 a1u = {q0, q1, q2, q3};
    u32x4 a2u = {q4, q5, q6, q7};
    short8 A1 = __builtin_bit_cast(short8, a1u);
    short8 A2 = __builtin_bit_cast(short8, a2u);
    int G1 = it * 4 + hi, G2 = G1 + 2;
    short8 v1 = *(const short8*)(Vt + vd * 512 + (((G1 & ~7) | ((G1 & 7) ^ (vd & 7)))) * 8);
    short8 v2 = *(const short8*)(Vt + vd * 512 + (((G2 & ~7) | ((G2 & 7) ^ (vd & 7)))) * 8);
    oacc = __builtin_amdgcn_mfma_f32_32x32x16_bf16(A1, v1, oacc, 0, 0, 0);
    oacc = __builtin_amdgcn_mfma_f32_32x32x16_bf16(A2, v2, oacc, 0, 0, 0);
  }
  lsum += __shfl_xor(lsum, 32, 64);
  float inv = __builtin_amdgcn_rcpf(lsum);
  float iv[16];
#pragma unroll
  for (int r = 0; r < 16; ++r) {
    int pl = (r & 3) + 8 * (r >> 2) + 4 * hi;
    iv[r] = __shfl(inv, pl, 64);
  }
  int b = bh >> 4, h = bh & 15;
  if (lo5 < 16) {
#pragma unroll
    for (int r = 0; r < 16; ++r) {
      int pl = (r & 3) + 8 * (r >> 2) + 4 * hi;
      u32 row = (u32)(b * 512 + p0 + pl);
      u32 k = (u32)(h * 16 + lo5);
      Ob[swz_off(row, k)] = f2bf(oacc[r] * iv[r]);
    }
  }
}

// C-projection: mh = (O @ Wc^T + bias)/16, written row-swizzled.
__global__ __launch_bounds__(256) void gemm_c_kernel(
    const u16* __restrict__ Obuf, const u16* __restrict__ Wcm,
    const float* __restrict__ Wcb, u16* __restrict__ mh_bf) {
  __shared__ __attribute__((aligned(16))) u16 Ws[16384];
  int bx = blockIdx.x;
  int jt = bx & 3, mt = (bx >> 2) & 3, b = bx >> 4;
  f32x4 acc[4][2];
  proj_core(Obuf + (b * 512 + mt * 128) * 256, Wcm + jt * 64 * 256, Ws, acc);
  int t = threadIdx.x, lane = t & 63, w = t >> 6;
  int wm = (w & 1) * 64, wj = (w >> 1) * 32, qq = lane >> 4, lr = lane & 15;
  for (int ms = 0; ms < 4; ++ms)
    for (int fj = 0; fj < 2; ++fj) {
      int e = jt * 64 + wj + fj * 16 + lr;
      float bias = Wcb[e];
      for (int r = 0; r < 4; ++r) {
        int p = mt * 128 + wm + ms * 16 + qq * 4 + r;
        mh_bf[swz_off((u32)(b * 512 + p), (u32)e)] = f2bf((acc[ms][fj][r] + bias) * 0.0625f);
      }
    }
}

// ---------------------------------------------------------------------------
// s2a: logits GEMM. logits[b][p][n] = (mh/16) . nodes  (fp32, 32MB in ws).
// ---------------------------------------------------------------------------
__global__ __launch_bounds__(256) void s2a_gemm_kernel(
    const u16* __restrict__ mh_bf, const u16* __restrict__ nodes_bf,
    float* __restrict__ lgbuf) {
  __shared__ __attribute__((aligned(16))) u16 Ws[16384];
  int bx = blockIdx.x;
  int jt = bx & 7, mt = (bx >> 3) & 3, b = bx >> 5;
  f32x4 acc[4][2];
  proj_core(mh_bf + (b * 512 + mt * 128) * 256,
            nodes_bf + ((u32)b * 512 + jt * 64) * 256, Ws, acc);
  int t = threadIdx.x, lane = t & 63, w = t >> 6;
  int wm = (w & 1) * 64, wj = (w >> 1) * 32, qq = lane >> 4, lr = lane & 15;
  for (int ms = 0; ms < 4; ++ms)
    for (int fj = 0; fj < 2; ++fj)
      for (int r = 0; r < 4; ++r) {
        int p = mt * 128 + wm + ms * 16 + qq * 4 + r;
        int n = jt * 64 + wj + fj * 16 + lr;
        lgbuf[((u32)b * 512 + p) * 512 + (u32)n] = acc[ms][fj][r];
      }
}

// ---------------------------------------------------------------------------
// s2b: streaming post. One wave per row (512 cols): exact 100-smallest
// binary search on cdist bits + tie-break quota (index order identical to
// reference top_k), penalty, tanh-clip, ninf, softmax, write. Zero LDS.
// ---------------------------------------------------------------------------
__global__ __launch_bounds__(256) void s2b_kernel(
    const float* __restrict__ lgbuf, const float* __restrict__ cdist,
    const float* __restrict__ ninf, float* __restrict__ out) {
  int t = threadIdx.x, lane = t & 63, w = t >> 6;
  long grow = (long)blockIdx.x * 4 + w;  // 0..16383 = b*512+p
  const u32* du = (const u32*)(cdist + grow * 512);
  const float* lgr = lgbuf + grow * 512;
  u32 u[8];
  float lgv[8];
#pragma unroll
  for (int i = 0; i < 8; ++i) u[i] = du[i * 64 + lane];
#pragma unroll
  for (int i = 0; i < 8; ++i) lgv[i] = lgr[i * 64 + lane];
  // exact 100-smallest threshold: radix binary search on fp32 bits
  u32 lo = 0u, hi_ = 0x3F800000u;  // uniform[0,1) upper bracket
  while (lo < hi_) {
    u32 mid = lo + ((hi_ - lo) >> 1);
    int cnt = 0;
#pragma unroll
    for (int i = 0; i < 8; ++i) cnt += __popcll(__ballot(u[i] <= mid));
    if (cnt >= 100) hi_ = mid; else lo = mid + 1;
  }
  u32 T = lo;
  int cl = 0;
#pragma unroll
  for (int i = 0; i < 8; ++i) cl += __popcll(__ballot(u[i] < T));
  int quota = 100 - cl;
  u64 lm = (1ull << lane) - 1ull;
  int eqacc = 0;
  const float* nr = ninf + grow * 512;
  float ex[8];
  float s = 0.f;
#pragma unroll
  for (int i = 0; i < 8; ++i) {
    u64 e = __ballot(u[i] == T);
    bool sel = (u[i] < T) || ((u[i] == T) && ((eqacc + __popcll(e & lm)) < quota));
    eqacc += __popcll(e);
    float dv = __builtin_bit_cast(float, u[i]);
    float x = lgv[i] + (sel ? -dv * INV_SQRT2 : 1.0f);
    float lgt = 10.0f * fast_tanh(x) + nr[i * 64 + lane];
    ex[i] = __builtin_amdgcn_exp2f(lgt * LOG2E);
    s += ex[i];
  }
  for (int m = 1; m < 64; m <<= 1) s += __shfl_xor(s, m, 64);
  float inv = 1.0f / s;
  float* orow = out + grow * 512;
#pragma unroll
  for (int i = 0; i < 8; ++i) orow[i * 64 + lane] = ex[i] * inv;
}

// ---------------------------------------------------------------------------
extern "C" void kernel_launch(void* const* d_in, const int* in_sizes, int n_in,
                              void* d_out, int out_size, void* d_ws, size_t ws_size,
                              hipStream_t stream) {
  const float* nodes = (const float*)d_in[0];
  const float* last  = (const float*)d_in[1];
  const float* loadv = (const float*)d_in[2];
  const float* cdist = (const float*)d_in[3];
  const float* ninf  = (const float*)d_in[6];
  const float* Wq    = (const float*)d_in[7];
  const float* Wk    = (const float*)d_in[8];
  const float* Wv    = (const float*)d_in[9];
  const float* Wc    = (const float*)d_in[10];
  const float* Wcb   = (const float*)d_in[11];

  char* ws = (char*)d_ws;
  u16* nodes_bf = (u16*)(ws + 0);
  u16* last_bf  = (u16*)(ws + 8388608);
  u16* Qbuf     = (u16*)(ws + 16777216);
  u16* Kbuf     = (u16*)(ws + 25165824);
  u16* Vbuf     = (u16*)(ws + 33554432);
  u16* Obuf     = (u16*)(ws + 41943040);
  u16* mh_bf    = (u16*)(ws + 50331648);
  u16* Wkv_bf   = (u16*)(ws + 58720256);
  u16* Wq_bf    = (u16*)(ws + 58982400);
  u16* Wc_bf    = (u16*)(ws + 59113472);
  float* wq_lc  = (float*)(ws + 59244544);
  // fp32 logits (32MB) reuse the dead Qbuf..Obuf region (s2a runs after
  // attn/gemm_c have consumed them).
  float* lgbuf  = (float*)(ws + 16777216);

  float* out = (float*)d_out;

  convert_kernel<<<4225, 256, 0, stream>>>(nodes, last, Wk, Wv, Wq, Wc,
                                           nodes_bf, last_bf, Wkv_bf, Wq_bf,
                                           wq_lc, Wc_bf);
  gemm_kv_kernel<<<1024, 256, 0, stream>>>(nodes_bf, Wkv_bf, Kbuf, Vbuf);
  gemm_q_kernel<<<512, 256, 0, stream>>>(last_bf, Wq_bf, wq_lc, loadv, Qbuf);
  attn_kernel<<<2048, 256, 0, stream>>>(Qbuf, Kbuf, Vbuf, Obuf);
  gemm_c_kernel<<<512, 256, 0, stream>>>(Obuf, Wc_bf, Wcb, mh_bf);
  s2a_gemm_kernel<<<1024, 256, 0, stream>>>(mh_bf, nodes_bf, lgbuf);
  s2b_kernel<<<4096, 256, 0, stream>>>(lgbuf, cdist, ninf, out);
}

// Round 4
// 257.257 us; speedup vs baseline: 1.1356x; 1.0410x over previous
//
#include <hip/hip_runtime.h>

// CVRP decoder v7, MI355X.
// Pipeline: convert -> proj_all -> attn -> s2a -> s2b   (5 dispatches).
// v7: structural. score2 = (O Wc^T + b) nodes^T re-associated to
// O (nodes Wc)^T + nodes.Wcb:  nc-GEMM depends only on nodes -> moves out
// of the serial tail into proj_all (merged kv|nc 768-channel GEMM + q GEMM
// + nb GEMV as grid segments, 2304 blocks = 9/CU). Tail is now
// attn -> s2a(O.nc^T + nb) -> s2b. gemm_c eliminated from critical path.

typedef unsigned short u16;
typedef unsigned int u32;
typedef unsigned long long u64;
typedef __attribute__((ext_vector_type(8))) short short8;
typedef __attribute__((ext_vector_type(4))) float f32x4;
typedef __attribute__((ext_vector_type(16))) float f32x16;
typedef __attribute__((ext_vector_type(4))) u32 u32x4;
typedef __attribute__((ext_vector_type(8))) u16 u16x8;

#define AS1U(p) ((const __attribute__((address_space(1))) u32*)(p))
#define AS3U(p) ((__attribute__((address_space(3))) u32*)(p))

#define QSCALE (0.25f * 1.44269504088896340736f)  // 1/sqrt(D) * log2(e)
#define LOG2E 1.44269504088896340736f
#define INV_SQRT2 0.70710678118654752440f

__device__ __forceinline__ u16 f2bf(float f) {
  u32 u = __builtin_bit_cast(u32, f);
  return (u16)((u + 0x7FFFu + ((u >> 16) & 1u)) >> 16);  // RNE
}

__device__ __forceinline__ u32 cvt_pk_bf16(float a, float b) {
  u32 r;
  asm("v_cvt_pk_bf16_f32 %0, %1, %2" : "=v"(r) : "v"(a), "v"(b));
  return r;  // lo = bf16(a), hi = bf16(b), RNE
}

__device__ __forceinline__ u32 swz_off(u32 row, u32 k) {  // half-index
  u32 g = k >> 3;
  u32 pos = (g & ~7u) | ((g & 7u) ^ (row & 7u));
  return row * 256u + pos * 8u + (k & 7u);
}

__device__ __forceinline__ float fast_tanh(float x) {
  float e = __builtin_amdgcn_exp2f(x * (2.0f * LOG2E));
  return 1.0f - 2.0f * __builtin_amdgcn_rcpf(e + 1.0f);
}

// ---------------------------------------------------------------------------
// convert: fp32 -> bf16, one 8-element granule per thread, swizzled rows.
// Wkvc = [Wk rows | Wv rows | Wc^T rows] (768 x 256).
// ---------------------------------------------------------------------------
__global__ __launch_bounds__(256) void convert_kernel(
    const float* __restrict__ nodes, const float* __restrict__ last,
    const float* __restrict__ Wk, const float* __restrict__ Wv,
    const float* __restrict__ Wq, const float* __restrict__ Wc,
    u16* __restrict__ nodes_bf, u16* __restrict__ last_bf,
    u16* __restrict__ Wkvc_bf, u16* __restrict__ Wq_bf,
    float* __restrict__ wq_last) {
  long i = (long)blockIdx.x * 256 + threadIdx.x;
  if (i < 524288) {  // nodes: 16384 rows x 32 granules
    u32 row = (u32)(i >> 5), g = (u32)(i & 31);
    const float4* s4 = (const float4*)nodes + i * 2;
    float4 v0 = s4[0], v1 = s4[1];
    u16x8 o = {f2bf(v0.x), f2bf(v0.y), f2bf(v0.z), f2bf(v0.w),
               f2bf(v1.x), f2bf(v1.y), f2bf(v1.z), f2bf(v1.w)};
    u32 pos = (g & ~7u) | ((g & 7u) ^ (row & 7u));
    *(u16x8*)(nodes_bf + row * 256 + pos * 8) = o;
  } else if (i < 1048576) {  // last
    long j = i - 524288;
    u32 row = (u32)(j >> 5), g = (u32)(j & 31);
    const float4* s4 = (const float4*)last + j * 2;
    float4 v0 = s4[0], v1 = s4[1];
    u16x8 o = {f2bf(v0.x), f2bf(v0.y), f2bf(v0.z), f2bf(v0.w),
               f2bf(v1.x), f2bf(v1.y), f2bf(v1.z), f2bf(v1.w)};
    u32 pos = (g & ~7u) | ((g & 7u) ^ (row & 7u));
    *(u16x8*)(last_bf + row * 256 + pos * 8) = o;
  } else if (i < 1073152) {  // Wkvc: 768 rows (Wk | Wv | Wc^T)
    long j = i - 1048576;
    u32 row = (u32)(j >> 5), g = (u32)(j & 31);
    u16x8 o;
    if (row < 256) {
      const float* src = Wk + row * 256 + g * 8;
      for (int q = 0; q < 8; q++) o[q] = f2bf(src[q]);
    } else if (row < 512) {
      const float* src = Wv + (row - 256) * 256 + g * 8;
      for (int q = 0; q < 8; q++) o[q] = f2bf(src[q]);
    } else {  // Wc^T: row k holds Wc[:, k] (src stride 256)
      u32 k = row - 512;
      const float* src = Wc + (u32)(g * 8) * 256 + k;
      for (int q = 0; q < 8; q++) o[q] = f2bf(src[(u32)q * 256]);
    }
    u32 pos = (g & ~7u) | ((g & 7u) ^ (row & 7u));
    *(u16x8*)(Wkvc_bf + row * 256 + pos * 8) = o;
  } else if (i < 1081344) {  // Wq main 256x256 (src stride 257)
    long j = i - 1073152;
    u32 row = (u32)(j >> 5), g = (u32)(j & 31);
    const float* src = Wq + row * 257 + g * 8;
    u16x8 o;
    for (int q = 0; q < 8; q++) o[q] = f2bf(src[q]);
    u32 pos = (g & ~7u) | ((g & 7u) ^ (row & 7u));
    *(u16x8*)(Wq_bf + row * 256 + pos * 8) = o;
  } else if (i < 1081600) {  // Wq last column (fp32)
    long o = i - 1081344;
    wq_last[o] = Wq[o * 257 + 256];
  }
}

// ---------------------------------------------------------------------------
// proj core: block computes 128m x 64j, K=256. W j-tile (64x256, 32KB) staged
// once in LDS via DMA + single barrier; A-frags direct global->VGPR.
// Wave (2x2): 64m x 32j -> acc[4 msub][2 fj]. Zero in-loop barriers.
// ---------------------------------------------------------------------------
__device__ __forceinline__ void proj_core(
    const u16* __restrict__ Abase, const u16* __restrict__ Wbase,
    u16* Ws, f32x4 acc[4][2]) {
  const int t = threadIdx.x;
  const int lane = t & 63, w = t >> 6;
  const int wm = (w & 1) * 64, wj = (w >> 1) * 32;
  const int qq = lane >> 4, lr = lane & 15;
#pragma unroll
  for (int c = 0; c < 8; ++c)
    __builtin_amdgcn_global_load_lds(AS1U(Wbase + c * 2048 + t * 8),
                                     AS3U(Ws + c * 2048 + w * 512), 16, 0, 0);
#pragma unroll
  for (int ms = 0; ms < 4; ++ms)
    for (int fj = 0; fj < 2; ++fj) acc[ms][fj] = (f32x4){0.f, 0.f, 0.f, 0.f};
  __syncthreads();
#pragma unroll
  for (int kt = 0; kt < 8; ++kt) {
    int g = kt * 4 + qq;
    int pos = (g & ~7) | ((g & 7) ^ (lr & 7));
    short8 av[4];
#pragma unroll
    for (int ms = 0; ms < 4; ++ms)
      av[ms] = *(const short8*)(Abase + (wm + ms * 16 + lr) * 256 + pos * 8);
    short8 b0 = *(const short8*)(Ws + (wj + lr) * 256 + pos * 8);
    short8 b1 = *(const short8*)(Ws + (wj + 16 + lr) * 256 + pos * 8);
#pragma unroll
    for (int ms = 0; ms < 4; ++ms) {
      acc[ms][0] = __builtin_amdgcn_mfma_f32_16x16x32_bf16(av[ms], b0, acc[ms][0], 0, 0, 0);
      acc[ms][1] = __builtin_amdgcn_mfma_f32_16x16x32_bf16(av[ms], b1, acc[ms][1], 0, 0, 0);
    }
  }
}

// ---------------------------------------------------------------------------
// proj_all: three grid segments.
//  [0,1536):   kvc GEMM: nodes_bf x Wkvc(768ch) -> Kbuf | Vbuf | ncbuf
//  [1536,2048): q GEMM:  last_bf x Wq -> Qbuf (pre-scaled)
//  [2048,2304): nb GEMV: nodes(fp32) . Wcb -> nb[16384]
// ---------------------------------------------------------------------------
__global__ __launch_bounds__(256) void proj_all_kernel(
    const u16* __restrict__ nodes_bf, const u16* __restrict__ last_bf,
    const u16* __restrict__ Wkvc, const u16* __restrict__ Wqm,
    const float* __restrict__ wq_last, const float* __restrict__ loadv,
    const float* __restrict__ nodes_f32, const float* __restrict__ Wcb,
    u16* __restrict__ Kbuf, u16* __restrict__ Vbuf, u16* __restrict__ ncbuf,
    u16* __restrict__ Qbuf, float* __restrict__ nb) {
  __shared__ __attribute__((aligned(16))) u16 Ws[16384];
  int bx = blockIdx.x;
  int t = threadIdx.x, lane = t & 63, w = t >> 6;
  if (bx >= 2048) {  // nb GEMV: 256 blocks x 4 waves x 16 rows
    int rbase = (bx - 2048) * 64 + w * 16;
    float4 cb = *(const float4*)(Wcb + lane * 4);
#pragma unroll
    for (int i = 0; i < 16; i += 4) {
      float4 f0 = *(const float4*)(nodes_f32 + (long)(rbase + i + 0) * 256 + lane * 4);
      float4 f1 = *(const float4*)(nodes_f32 + (long)(rbase + i + 1) * 256 + lane * 4);
      float4 f2 = *(const float4*)(nodes_f32 + (long)(rbase + i + 2) * 256 + lane * 4);
      float4 f3 = *(const float4*)(nodes_f32 + (long)(rbase + i + 3) * 256 + lane * 4);
      float p0 = f0.x * cb.x + f0.y * cb.y + f0.z * cb.z + f0.w * cb.w;
      float p1 = f1.x * cb.x + f1.y * cb.y + f1.z * cb.z + f1.w * cb.w;
      float p2 = f2.x * cb.x + f2.y * cb.y + f2.z * cb.z + f2.w * cb.w;
      float p3 = f3.x * cb.x + f3.y * cb.y + f3.z * cb.z + f3.w * cb.w;
#pragma unroll
      for (int m = 1; m < 64; m <<= 1) {
        p0 += __shfl_xor(p0, m, 64);
        p1 += __shfl_xor(p1, m, 64);
        p2 += __shfl_xor(p2, m, 64);
        p3 += __shfl_xor(p3, m, 64);
      }
      if (lane == 0) {
        nb[rbase + i + 0] = p0;
        nb[rbase + i + 1] = p1;
        nb[rbase + i + 2] = p2;
        nb[rbase + i + 3] = p3;
      }
    }
    return;
  }
  int wm = (w & 1) * 64, wj = (w >> 1) * 32, qq = lane >> 4, lr = lane & 15;
  f32x4 acc[4][2];
  if (bx < 1536) {  // kvc
    int jt = bx % 12, rem = bx / 12;
    int mt = rem & 3, b = rem >> 2;
    proj_core(nodes_bf + (b * 512 + mt * 128) * 256, Wkvc + jt * 64 * 256, Ws, acc);
    for (int ms = 0; ms < 4; ++ms)
      for (int fj = 0; fj < 2; ++fj) {
        int j = jt * 64 + wj + fj * 16 + lr;
        for (int r = 0; r < 4; ++r) {
          int n = mt * 128 + wm + ms * 16 + qq * 4 + r;
          u16 val = f2bf(acc[ms][fj][r]);
          if (j < 256) {
            int h = j >> 4, d = j & 15;
            Kbuf[(u32)(b * 16 + h) * 8192 + (u32)(n >> 5) * 512 +
                 (u32)(d >> 3) * 256 + (u32)(n & 31) * 8 + (u32)(d & 7)] = val;
          } else if (j < 512) {
            int o = j - 256, h = o >> 4, d = o & 15;
            u32 G = (u32)(n >> 3);
            u32 pos = (G & ~7u) | ((G & 7u) ^ ((u32)d & 7u));
            Vbuf[(u32)(b * 16 + h) * 8192 + (u32)d * 512 + pos * 8 + (u32)(n & 7)] = val;
          } else {
            ncbuf[swz_off((u32)(b * 512 + n), (u32)(j - 512))] = val;
          }
        }
      }
  } else {  // q
    int bx2 = bx - 1536;
    int jt = bx2 & 3, mt = (bx2 >> 2) & 3, b = bx2 >> 4;
    proj_core(last_bf + (b * 512 + mt * 128) * 256, Wqm + jt * 64 * 256, Ws, acc);
    for (int ms = 0; ms < 4; ++ms)
      for (int fj = 0; fj < 2; ++fj) {
        int o = jt * 64 + wj + fj * 16 + lr;
        float wql = wq_last[o];
        for (int r = 0; r < 4; ++r) {
          int p = mt * 128 + wm + ms * 16 + qq * 4 + r;
          float ld = loadv[b * 512 + p];
          float v = (acc[ms][fj][r] + ld * wql) * QSCALE;
          Qbuf[((b * 16 + (o >> 4)) * 512 + p) * 16 + (o & 15)] = f2bf(v);
        }
      }
  }
}

// ---------------------------------------------------------------------------
// Attention: one (b,h, p-tile-of-128) per block; wave = 32 Q-rows.
// S^T = K*Q^T via mfma_32x32x16 (K=16==D). P relayout in registers via
// v_cvt_pk_bf16_f32 + v_permlane32_swap_b32 (T12). exp2 path, no
// max-subtraction (|score| small). O written row-swizzled to Obuf.
// ---------------------------------------------------------------------------
__global__ __launch_bounds__(256) void attn_kernel(
    const u16* __restrict__ Qb, const u16* __restrict__ Kb,
    const u16* __restrict__ Vb, u16* __restrict__ Ob) {
  __shared__ __attribute__((aligned(16))) u16 Ks[8192];
  __shared__ __attribute__((aligned(16))) u16 Vt[8192];
  int bx = blockIdx.x;
  int pt = bx & 3, bh = bx >> 2;
  int t = threadIdx.x, lane = t & 63, w = t >> 6;
  int lo5 = lane & 31, hi = lane >> 5;
  int vd = lane & 15;
  for (int c = 0; c < 4; ++c) {
    __builtin_amdgcn_global_load_lds(AS1U(Kb + bh * 8192 + c * 2048 + t * 8),
                                     AS3U(Ks + c * 2048 + w * 512), 16, 0, 0);
    __builtin_amdgcn_global_load_lds(AS1U(Vb + bh * 8192 + c * 2048 + t * 8),
                                     AS3U(Vt + c * 2048 + w * 512), 16, 0, 0);
  }
  int p0 = pt * 128 + w * 32;
  short8 qf = *(const short8*)(Qb + bh * 8192 + (p0 + lo5) * 16 + hi * 8);
  __syncthreads();
  f32x16 oacc = {};
  float lsum = 0.f;
  for (int it = 0; it < 16; ++it) {
    short8 kf = *(const short8*)(Ks + it * 512 + lane * 8);
    f32x16 st = __builtin_amdgcn_mfma_f32_32x32x16_bf16(kf, qf, (f32x16){}, 0, 0, 0);
    float ev[16];
    float ls = 0.f;
#pragma unroll
    for (int r = 0; r < 16; ++r) ev[r] = __builtin_amdgcn_exp2f(st[r]);
#pragma unroll
    for (int r = 0; r < 16; ++r) ls += ev[r];
    lsum += ls;
    u32 q0 = cvt_pk_bf16(ev[0], ev[1]);
    u32 q1 = cvt_pk_bf16(ev[2], ev[3]);
    u32 q2 = cvt_pk_bf16(ev[4], ev[5]);
    u32 q3 = cvt_pk_bf16(ev[6], ev[7]);
    u32 q4 = cvt_pk_bf16(ev[8], ev[9]);
    u32 q5 = cvt_pk_bf16(ev[10], ev[11]);
    u32 q6 = cvt_pk_bf16(ev[12], ev[13]);
    u32 q7 = cvt_pk_bf16(ev[14], ev[15]);
    asm("v_permlane32_swap_b32 %0, %1" : "+v"(q0), "+v"(q2));
    asm("v_permlane32_swap_b32 %0, %1" : "+v"(q1), "+v"(q3));
    asm("v_permlane32_swap_b32 %0, %1" : "+v"(q4), "+v"(q6));
    asm("v_permlane32_swap_b32 %0, %1" : "+v"(q5), "+v"(q7));
    u32x4 a1u = {q0, q1, q2, q3};
    u32x4 a2u = {q4, q5, q6, q7};
    short8 A1 = __builtin_bit_cast(short8, a1u);
    short8 A2 = __builtin_bit_cast(short8, a2u);
    int G1 = it * 4 + hi, G2 = G1 + 2;
    short8 v1 = *(const short8*)(Vt + vd * 512 + (((G1 & ~7) | ((G1 & 7) ^ (vd & 7)))) * 8);
    short8 v2 = *(const short8*)(Vt + vd * 512 + (((G2 & ~7) | ((G2 & 7) ^ (vd & 7)))) * 8);
    oacc = __builtin_amdgcn_mfma_f32_32x32x16_bf16(A1, v1, oacc, 0, 0, 0);
    oacc = __builtin_amdgcn_mfma_f32_32x32x16_bf16(A2, v2, oacc, 0, 0, 0);
  }
  lsum += __shfl_xor(lsum, 32, 64);
  float inv = __builtin_amdgcn_rcpf(lsum);
  float iv[16];
#pragma unroll
  for (int r = 0; r < 16; ++r) {
    int pl = (r & 3) + 8 * (r >> 2) + 4 * hi;
    iv[r] = __shfl(inv, pl, 64);
  }
  int b = bh >> 4, h = bh & 15;
  if (lo5 < 16) {
#pragma unroll
    for (int r = 0; r < 16; ++r) {
      int pl = (r & 3) + 8 * (r >> 2) + 4 * hi;
      u32 row = (u32)(b * 512 + p0 + pl);
      u32 k = (u32)(h * 16 + lo5);
      Ob[swz_off(row, k)] = f2bf(oacc[r] * iv[r]);
    }
  }
}

// ---------------------------------------------------------------------------
// s2a: score_scaled = (O . nc^T + nb) / 16  (fp32 -> lgbuf).
// A = Obuf (row-swizzled), W-tile = 64 nc rows (row-swizzled, LDS-staged).
// ---------------------------------------------------------------------------
__global__ __launch_bounds__(256) void s2a_gemm_kernel(
    const u16* __restrict__ Obuf, const u16* __restrict__ ncbuf,
    const float* __restrict__ nb, float* __restrict__ lgbuf) {
  __shared__ __attribute__((aligned(16))) u16 Ws[16384];
  int bx = blockIdx.x;
  int jt = bx & 7, mt = (bx >> 3) & 3, b = bx >> 5;
  f32x4 acc[4][2];
  proj_core(Obuf + (b * 512 + mt * 128) * 256,
            ncbuf + ((u32)b * 512 + jt * 64) * 256, Ws, acc);
  int t = threadIdx.x, lane = t & 63, w = t >> 6;
  int wm = (w & 1) * 64, wj = (w >> 1) * 32, qq = lane >> 4, lr = lane & 15;
  for (int ms = 0; ms < 4; ++ms)
    for (int fj = 0; fj < 2; ++fj) {
      int n = jt * 64 + wj + fj * 16 + lr;
      float nbv = nb[b * 512 + n];
      for (int r = 0; r < 4; ++r) {
        int p = mt * 128 + wm + ms * 16 + qq * 4 + r;
        lgbuf[((u32)b * 512 + p) * 512 + (u32)n] = (acc[ms][fj][r] + nbv) * 0.0625f;
      }
    }
}

// ---------------------------------------------------------------------------
// s2b: streaming post. One wave per row (512 cols): exact 100-smallest
// binary search on cdist bits + tie-break quota (index order identical to
// reference top_k), penalty, tanh-clip, ninf, softmax, write. Zero LDS.
// ---------------------------------------------------------------------------
__global__ __launch_bounds__(256) void s2b_kernel(
    const float* __restrict__ lgbuf, const float* __restrict__ cdist,
    const float* __restrict__ ninf, float* __restrict__ out) {
  int t = threadIdx.x, lane = t & 63, w = t >> 6;
  long grow = (long)blockIdx.x * 4 + w;  // 0..16383 = b*512+p
  const u32* du = (const u32*)(cdist + grow * 512);
  const float* lgr = lgbuf + grow * 512;
  u32 u[8];
  float lgv[8];
#pragma unroll
  for (int i = 0; i < 8; ++i) u[i] = du[i * 64 + lane];
#pragma unroll
  for (int i = 0; i < 8; ++i) lgv[i] = lgr[i * 64 + lane];
  // exact 100-smallest threshold: radix binary search on fp32 bits
  u32 lo = 0u, hi_ = 0x3F800000u;  // uniform[0,1) upper bracket
  while (lo < hi_) {
    u32 mid = lo + ((hi_ - lo) >> 1);
    int cnt = 0;
#pragma unroll
    for (int i = 0; i < 8; ++i) cnt += __popcll(__ballot(u[i] <= mid));
    if (cnt >= 100) hi_ = mid; else lo = mid + 1;
  }
  u32 T = lo;
  int cl = 0;
#pragma unroll
  for (int i = 0; i < 8; ++i) cl += __popcll(__ballot(u[i] < T));
  int quota = 100 - cl;
  u64 lm = (1ull << lane) - 1ull;
  int eqacc = 0;
  const float* nr = ninf + grow * 512;
  float ex[8];
  float s = 0.f;
#pragma unroll
  for (int i = 0; i < 8; ++i) {
    u64 e = __ballot(u[i] == T);
    bool sel = (u[i] < T) || ((u[i] == T) && ((eqacc + __popcll(e & lm)) < quota));
    eqacc += __popcll(e);
    float dv = __builtin_bit_cast(float, u[i]);
    float x = lgv[i] + (sel ? -dv * INV_SQRT2 : 1.0f);
    float lgt = 10.0f * fast_tanh(x) + nr[i * 64 + lane];
    ex[i] = __builtin_amdgcn_exp2f(lgt * LOG2E);
    s += ex[i];
  }
  for (int m = 1; m < 64; m <<= 1) s += __shfl_xor(s, m, 64);
  float inv = 1.0f / s;
  float* orow = out + grow * 512;
#pragma unroll
  for (int i = 0; i < 8; ++i) orow[i * 64 + lane] = ex[i] * inv;
}

// ---------------------------------------------------------------------------
extern "C" void kernel_launch(void* const* d_in, const int* in_sizes, int n_in,
                              void* d_out, int out_size, void* d_ws, size_t ws_size,
                              hipStream_t stream) {
  const float* nodes = (const float*)d_in[0];
  const float* last  = (const float*)d_in[1];
  const float* loadv = (const float*)d_in[2];
  const float* cdist = (const float*)d_in[3];
  const float* ninf  = (const float*)d_in[6];
  const float* Wq    = (const float*)d_in[7];
  const float* Wk    = (const float*)d_in[8];
  const float* Wv    = (const float*)d_in[9];
  const float* Wc    = (const float*)d_in[10];
  const float* Wcb   = (const float*)d_in[11];

  char* ws = (char*)d_ws;
  u16* nodes_bf = (u16*)(ws + 0);          // 8.39 MB
  u16* last_bf  = (u16*)(ws + 8388608);    // 8.39 MB
  u16* Qbuf     = (u16*)(ws + 16777216);   // 8.39 MB
  u16* Kbuf     = (u16*)(ws + 25165824);   // 8.39 MB
  u16* Vbuf     = (u16*)(ws + 33554432);   // 8.39 MB
  u16* Obuf     = (u16*)(ws + 41943040);   // 8.39 MB
  u16* ncbuf    = (u16*)(ws + 50331648);   // 8.39 MB
  u16* Wkvc_bf  = (u16*)(ws + 58720256);   // 384 KB
  u16* Wq_bf    = (u16*)(ws + 59113472);   // 128 KB
  float* wq_lc  = (float*)(ws + 59244544); // 1 KB
  float* nb     = (float*)(ws + 59245568); // 64 KB
  float* lgbuf  = (float*)(ws + 67108864); // 33.55 MB (fresh region)

  float* out = (float*)d_out;

  convert_kernel<<<4225, 256, 0, stream>>>(nodes, last, Wk, Wv, Wq, Wc,
                                           nodes_bf, last_bf, Wkvc_bf, Wq_bf,
                                           wq_lc);
  proj_all_kernel<<<2304, 256, 0, stream>>>(nodes_bf, last_bf, Wkvc_bf, Wq_bf,
                                            wq_lc, loadv, nodes, Wcb,
                                            Kbuf, Vbuf, ncbuf, Qbuf, nb);
  attn_kernel<<<2048, 256, 0, stream>>>(Qbuf, Kbuf, Vbuf, Obuf);
  s2a_gemm_kernel<<<1024, 256, 0, stream>>>(Obuf, ncbuf, nb, lgbuf);
  s2b_kernel<<<4096, 256, 0, stream>>>(lgbuf, cdist, ninf, out);
}